// Round 4
// baseline (520.311 us; speedup 1.0000x reference)
//
#include <hip/hip_runtime.h>
#include <hip/hip_bf16.h>
#include <cstdint>
#include <cstddef>

typedef unsigned short u16;
typedef short s16x8 __attribute__((ext_vector_type(8)));
typedef float f32x4 __attribute__((ext_vector_type(4)));

#define HIDDEN_C 2048
#define TSEQ 2048
#define BATCH 2
#define NHEADS 16
#define NKV 4
#define HDIM 128
#define NQKV 3072
#define BTR 4096  // BATCH*TSEQ

__device__ __forceinline__ float bf2f(u16 u) {
  union { uint32_t i; float f; } v; v.i = ((uint32_t)u) << 16; return v.f;
}
__device__ __forceinline__ u16 f2bf(float f) {
  union { float f; uint32_t i; } v; v.f = f;
  uint32_t r = v.i + 0x7fffu + ((v.i >> 16) & 1u);
  return (u16)(r >> 16);
}

// DPP cross-lane (within 16-lane row): returns v from lane^k
template <int CTRL>
__device__ __forceinline__ float dpp_xor(float v) {
  int x = __builtin_amdgcn_update_dpp(0, __builtin_bit_cast(int, v), CTRL, 0xf, 0xf, true);
  return __builtin_bit_cast(float, x);
}
#define DPP_XOR1 0xB1   // quad_perm [1,0,3,2]
#define DPP_XOR2 0x4E   // quad_perm [2,3,0,1]
#define DPP_HMIR 0x141  // row_half_mirror (i^7; valid once 4-groups uniform)
#define DPP_MIR  0x140  // row_mirror      (i^15; valid once 8-groups uniform)

#define AS1(p) ((__attribute__((address_space(1))) void*)(uintptr_t)(p))
#define AS3(p) ((__attribute__((address_space(3))) void*)(p))

// ---------------- fp32 -> bf16 convert (8 elems/thread) ----------------
__global__ void convert_x_kernel(const float* __restrict__ x, u16* __restrict__ xb) {
  int i = (blockIdx.x * blockDim.x + threadIdx.x) * 8;
  float4 a = *(const float4*)(x + i);
  float4 b = *(const float4*)(x + i + 4);
  uint4 o;
  o.x = (uint32_t)f2bf(a.x) | ((uint32_t)f2bf(a.y) << 16);
  o.y = (uint32_t)f2bf(a.z) | ((uint32_t)f2bf(a.w) << 16);
  o.z = (uint32_t)f2bf(b.x) | ((uint32_t)f2bf(b.y) << 16);
  o.w = (uint32_t)f2bf(b.z) | ((uint32_t)f2bf(b.w) << 16);
  *(uint4*)(xb + i) = o;
}

// ---------------- W [R][C] fp32 -> W^T [C][R] bf16 ----------------
__global__ void transpose_w_kernel(const float* __restrict__ in, u16* __restrict__ out,
                                   int R, int C) {
  __shared__ float tile[32][33];
  int r0 = blockIdx.y * 32, c0 = blockIdx.x * 32;
  int tx = threadIdx.x, ty = threadIdx.y;
  #pragma unroll
  for (int i = 0; i < 32; i += 8)
    tile[ty + i][tx] = in[(size_t)(r0 + ty + i) * C + c0 + tx];
  __syncthreads();
  #pragma unroll
  for (int i = 0; i < 32; i += 8)
    out[(size_t)(c0 + ty + i) * R + r0 + tx] = f2bf(tile[tx][ty + i]);
}

// ---------------- GEMM: C[M][N] = A[M][K] * BT[N][K]^T (bf16 in, OutT out) -------
template <typename OutT>
__global__ __launch_bounds__(256) void gemm_bt_kernel(const u16* __restrict__ A,
                                                      const u16* __restrict__ BT,
                                                      OutT* __restrict__ C,
                                                      int M, int N, int K) {
  __shared__ u16 As[128 * 32];
  __shared__ u16 Bs[128 * 32];
  const int tid = threadIdx.x;
  const int wave = tid >> 6, lane = tid & 63;
  const int lr = lane & 15, lg = lane >> 4;
  const int m0 = blockIdx.y * 128, n0 = blockIdx.x * 128;
  const int wr = wave >> 1, wc = wave & 1;
  f32x4 acc[4][4];
  #pragma unroll
  for (int a = 0; a < 4; ++a)
    #pragma unroll
    for (int b = 0; b < 4; ++b) acc[a][b] = (f32x4){0.f, 0.f, 0.f, 0.f};

  for (int k0 = 0; k0 < K; k0 += 32) {
    #pragma unroll
    for (int i = 0; i < 2; ++i) {
      int c = tid + i * 256;
      int row = c >> 2, col8 = (c & 3) * 8;
      const u16* gA = A + (size_t)(m0 + row) * K + k0 + col8;
      const u16* gB = BT + (size_t)(n0 + row) * K + k0 + col8;
      char* lA = (char*)As + ((size_t)(wave * 64 + i * 256)) * 16;
      char* lB = (char*)Bs + ((size_t)(wave * 64 + i * 256)) * 16;
      __builtin_amdgcn_global_load_lds(AS1(gA), AS3(lA), 16, 0, 0);
      __builtin_amdgcn_global_load_lds(AS1(gB), AS3(lB), 16, 0, 0);
    }
    __syncthreads();
    s16x8 af[4], bfr[4];
    #pragma unroll
    for (int mi = 0; mi < 4; ++mi)
      af[mi] = *(const s16x8*)(As + (wr * 64 + mi * 16 + lr) * 32 + lg * 8);
    #pragma unroll
    for (int ni = 0; ni < 4; ++ni)
      bfr[ni] = *(const s16x8*)(Bs + (wc * 64 + ni * 16 + lr) * 32 + lg * 8);
    #pragma unroll
    for (int mi = 0; mi < 4; ++mi)
      #pragma unroll
      for (int ni = 0; ni < 4; ++ni)
        acc[mi][ni] = __builtin_amdgcn_mfma_f32_16x16x32_bf16(af[mi], bfr[ni], acc[mi][ni], 0, 0, 0);
    __syncthreads();
  }
  #pragma unroll
  for (int mi = 0; mi < 4; ++mi) {
    int rowb = m0 + wr * 64 + mi * 16 + lg * 4;
    #pragma unroll
    for (int ni = 0; ni < 4; ++ni) {
      int col = n0 + wc * 64 + ni * 16 + lr;
      #pragma unroll
      for (int r = 0; r < 4; ++r) {
        float v = acc[mi][ni][r];
        if constexpr (sizeof(OutT) == 2) C[(size_t)(rowb + r) * N + col] = (OutT)f2bf(v);
        else                             C[(size_t)(rowb + r) * N + col] = v;
      }
    }
  }
}

// ---------------- RoPE (+optional scale), in-place on qkv ----------------
__global__ void rope_kernel(u16* __restrict__ base, int col_off, int head_shift, float scale) {
  int idx = blockIdx.x * blockDim.x + threadIdx.x;
  int quarter = idx & 3;
  int hidx = idx >> 2;
  int head = hidx & ((1 << head_shift) - 1);
  int bt = hidx >> head_shift;
  if (bt >= BTR) return;
  int t = bt & (TSEQ - 1);
  u16* p = base + (size_t)bt * NQKV + col_off + head * HDIM + quarter * 32;
  uint4 u[4];
  #pragma unroll
  for (int j = 0; j < 4; ++j) u[j] = ((const uint4*)p)[j];
  float v[32];
  #pragma unroll
  for (int j = 0; j < 4; ++j) {
    v[j*8+0] = bf2f((u16)(u[j].x & 0xffff)); v[j*8+1] = bf2f((u16)(u[j].x >> 16));
    v[j*8+2] = bf2f((u16)(u[j].y & 0xffff)); v[j*8+3] = bf2f((u16)(u[j].y >> 16));
    v[j*8+4] = bf2f((u16)(u[j].z & 0xffff)); v[j*8+5] = bf2f((u16)(u[j].z >> 16));
    v[j*8+6] = bf2f((u16)(u[j].w & 0xffff)); v[j*8+7] = bf2f((u16)(u[j].w >> 16));
  }
  if (quarter == 0) {
    #pragma unroll
    for (int i = 0; i < 16; ++i) {
      float f = powf(10000.f, -(float)i * (1.f / 16.f));
      float ang = (float)t * f;
      float s = sinf(ang), c = cosf(ang);
      float a = v[i], b = v[i + 16];
      v[i]      = a * c - b * s;
      v[i + 16] = b * c + a * s;
    }
  }
  #pragma unroll
  for (int i = 0; i < 32; ++i) v[i] *= scale;
  #pragma unroll
  for (int j = 0; j < 4; ++j) {
    u[j].x = (uint32_t)f2bf(v[j*8+0]) | ((uint32_t)f2bf(v[j*8+1]) << 16);
    u[j].y = (uint32_t)f2bf(v[j*8+2]) | ((uint32_t)f2bf(v[j*8+3]) << 16);
    u[j].z = (uint32_t)f2bf(v[j*8+4]) | ((uint32_t)f2bf(v[j*8+5]) << 16);
    u[j].w = (uint32_t)f2bf(v[j*8+6]) | ((uint32_t)f2bf(v[j*8+7]) << 16);
  }
  #pragma unroll
  for (int j = 0; j < 4; ++j) ((uint4*)p)[j] = u[j];
}

// ---------------- V [b][t][g][d] -> VT [b][g][d][t] ----------------
__global__ void transpose_v_kernel(const u16* __restrict__ qkv, u16* __restrict__ vt) {
  int bg = blockIdx.z;
  int b = bg >> 2, g = bg & 3;
  int t0 = blockIdx.x * 32, d0 = blockIdx.y * 32;
  __shared__ u16 tile[32][33];
  int tx = threadIdx.x, ty = threadIdx.y;
  #pragma unroll
  for (int i = 0; i < 32; i += 8)
    tile[ty + i][tx] = qkv[(size_t)(b * TSEQ + t0 + ty + i) * NQKV + 2560 + g * HDIM + d0 + tx];
  __syncthreads();
  #pragma unroll
  for (int i = 0; i < 32; i += 8)
    vt[((size_t)bg * HDIM + d0 + ty + i) * TSEQ + t0 + tx] = tile[tx][ty + i];
}

// ---------------- flash attention v4 ----------------
// 4 waves x 32 Q-rows; KVBLK=64; K LDS-dbuf (XOR swizzle, pre-swizzled source);
// V direct from global (L2-hot); DPP softmax reduces; 48KB LDS -> 3 blocks/CU.
__global__ __launch_bounds__(256, 3) void attn_kernel(const u16* __restrict__ qkv,
                                                      const u16* __restrict__ vt,
                                                      u16* __restrict__ attn_out) {
  __shared__ u16 K_lds[2][64][128];   // [buf][kpos][d]   32 KB
  __shared__ u16 P_lds[4][32][64];    // per-wave P tile  16 KB

  const int b = blockIdx.z, h = blockIdx.y, g = h >> 2;
  const int tid = threadIdx.x, w = tid >> 6, lane = tid & 63;
  const int lr = lane & 15, lg = lane >> 4;
  const int tile = (int)gridDim.x - 1 - (int)blockIdx.x;  // longest first
  const int q0 = tile * 128;
  const int q0w = q0 + w * 32;

  const u16* Qg = qkv + (size_t)b * TSEQ * NQKV + h * HDIM;
  const u16* Kg = qkv + (size_t)b * TSEQ * NQKV + HIDDEN_C + g * HDIM;
  const u16* Vg = vt + (size_t)(b * NKV + g) * HDIM * TSEQ;

  s16x8 aq[2][4];
  #pragma unroll
  for (int mi = 0; mi < 2; ++mi) {
    const u16* qrow = Qg + (size_t)(q0w + mi * 16 + lr) * NQKV + lg * 8;
    #pragma unroll
    for (int kk = 0; kk < 4; ++kk) aq[mi][kk] = *(const s16x8*)(qrow + kk * 32);
  }

  f32x4 O[2][8];
  #pragma unroll
  for (int mi = 0; mi < 2; ++mi)
    #pragma unroll
    for (int dt = 0; dt < 8; ++dt) O[mi][dt] = (f32x4){0.f, 0.f, 0.f, 0.f};
  float m_r[2][4], l_r[2][4];
  #pragma unroll
  for (int mi = 0; mi < 2; ++mi)
    #pragma unroll
    for (int r = 0; r < 4; ++r) { m_r[mi][r] = -1e30f; l_r[mi][r] = 0.f; }

  // stage K k-block kb into buffer `buf`; LDS linear, source pre-swizzled
  auto STAGE = [&](int buf, int kb) {
    #pragma unroll
    for (int i = 0; i < 4; ++i) {          // K: 64 rows x 16 chunks of 16B
      int c = tid + i * 256;
      int row = c >> 4, slot = c & 15;
      int gslot = slot ^ (row & 7);
      const u16* src = Kg + (size_t)(kb + row) * NQKV + gslot * 8;
      char* dst = (char*)&K_lds[buf][0][0] + (size_t)c * 16;
      __builtin_amdgcn_global_load_lds(AS1(src), AS3(dst), 16, 0, 0);
    }
  };

  const int nt = (q0 + 128) / 64;  // causal: k < q0+128
  STAGE(0, 0);
  asm volatile("s_waitcnt vmcnt(0)" ::: "memory");
  __syncthreads();

  for (int t = 0; t < nt; ++t) {
    const int kb = t * 64;
    const int cur = t & 1;
    if (t + 1 < nt) STAGE(cur ^ 1, kb + 64);

    if (kb <= q0w + 31) {
      // ---- QK^T ----
      f32x4 S[2][4];
      #pragma unroll
      for (int mi = 0; mi < 2; ++mi)
        #pragma unroll
        for (int ni = 0; ni < 4; ++ni) S[mi][ni] = (f32x4){0.f, 0.f, 0.f, 0.f};
      __builtin_amdgcn_s_setprio(1);
      #pragma unroll
      for (int ni = 0; ni < 4; ++ni) {
        const u16* krow = &K_lds[cur][ni * 16 + lr][0];
        #pragma unroll
        for (int kk = 0; kk < 4; ++kk) {
          s16x8 bk = *(const s16x8*)(krow + ((kk * 32 + lg * 8) ^ ((lr & 7) << 3)));
          #pragma unroll
          for (int mi = 0; mi < 2; ++mi)
            S[mi][ni] = __builtin_amdgcn_mfma_f32_16x16x32_bf16(aq[mi][kk], bk, S[mi][ni], 0, 0, 0);
        }
      }
      __builtin_amdgcn_s_setprio(0);
      // ---- causal mask ----
      if (kb + 63 > q0w) {
        #pragma unroll
        for (int mi = 0; mi < 2; ++mi)
          #pragma unroll
          for (int r = 0; r < 4; ++r) {
            int rr = q0w + mi * 16 + lg * 4 + r;
            #pragma unroll
            for (int ni = 0; ni < 4; ++ni) {
              int cc = kb + ni * 16 + lr;
              if (cc > rr) S[mi][ni][r] = -1e30f;
            }
          }
      }
      // ---- online softmax: DPP butterflies within 16-lane rows ----
      float alpha[2][4];
      #pragma unroll
      for (int mi = 0; mi < 2; ++mi)
        #pragma unroll
        for (int r = 0; r < 4; ++r) {
          float v = fmaxf(fmaxf(S[mi][0][r], S[mi][1][r]), fmaxf(S[mi][2][r], S[mi][3][r]));
          v = fmaxf(v, dpp_xor<DPP_XOR1>(v));
          v = fmaxf(v, dpp_xor<DPP_XOR2>(v));
          v = fmaxf(v, dpp_xor<DPP_HMIR>(v));
          v = fmaxf(v, dpp_xor<DPP_MIR>(v));
          float mn = fmaxf(m_r[mi][r], v);
          float al = __expf(m_r[mi][r] - mn);
          m_r[mi][r] = mn;
          float ps = 0.f;
          #pragma unroll
          for (int ni = 0; ni < 4; ++ni) {
            float p = __expf(S[mi][ni][r] - mn);
            S[mi][ni][r] = p;
            ps += p;
          }
          ps += dpp_xor<DPP_XOR1>(ps);
          ps += dpp_xor<DPP_XOR2>(ps);
          ps += dpp_xor<DPP_HMIR>(ps);
          ps += dpp_xor<DPP_MIR>(ps);
          l_r[mi][r] = l_r[mi][r] * al + ps;
          alpha[mi][r] = al;
        }
      #pragma unroll
      for (int mi = 0; mi < 2; ++mi)
        #pragma unroll
        for (int dt = 0; dt < 8; ++dt)
          #pragma unroll
          for (int r = 0; r < 4; ++r) O[mi][dt][r] *= alpha[mi][r];
      // ---- P -> LDS (swizzled scalar writes) ----
      u16* pw = &P_lds[w][0][0];
      #pragma unroll
      for (int mi = 0; mi < 2; ++mi)
        #pragma unroll
        for (int r = 0; r < 4; ++r) {
          int qrl = mi * 16 + lg * 4 + r;
          int sw = (qrl & 7) << 3;
          #pragma unroll
          for (int ni = 0; ni < 4; ++ni)
            pw[qrl * 64 + ((ni * 16 + lr) ^ sw)] = f2bf(S[mi][ni][r]);
        }
      asm volatile("s_waitcnt lgkmcnt(0)" ::: "memory");
      __builtin_amdgcn_sched_barrier(0);
      // ---- PV: P from LDS, V direct from global (L2-hot) ----
      s16x8 pa[2][2];
      #pragma unroll
      for (int mi = 0; mi < 2; ++mi) {
        const u16* prow = &P_lds[w][mi * 16 + lr][0];
        #pragma unroll
        for (int ks = 0; ks < 2; ++ks)
          pa[mi][ks] = *(const s16x8*)(prow + ((ks * 32 + lg * 8) ^ ((lr & 7) << 3)));
      }
      __builtin_amdgcn_s_setprio(1);
      #pragma unroll
      for (int dt = 0; dt < 8; ++dt) {
        const u16* vrow = Vg + (size_t)(dt * 16 + lr) * TSEQ + kb + lg * 8;
        #pragma unroll
        for (int ks = 0; ks < 2; ++ks) {
          s16x8 bv = *(const s16x8*)(vrow + ks * 32);
          #pragma unroll
          for (int mi = 0; mi < 2; ++mi)
            O[mi][dt] = __builtin_amdgcn_mfma_f32_16x16x32_bf16(pa[mi][ks], bv, O[mi][dt], 0, 0, 0);
        }
      }
      __builtin_amdgcn_s_setprio(0);
    }
    asm volatile("s_waitcnt vmcnt(0)" ::: "memory");
    __syncthreads();
  }

  float invl[2][4];
  #pragma unroll
  for (int mi = 0; mi < 2; ++mi)
    #pragma unroll
    for (int r = 0; r < 4; ++r) invl[mi][r] = 1.f / l_r[mi][r];
  #pragma unroll
  for (int mi = 0; mi < 2; ++mi)
    #pragma unroll
    for (int dt = 0; dt < 8; ++dt)
      #pragma unroll
      for (int r = 0; r < 4; ++r) {
        float v = O[mi][dt][r] * invl[mi][r];
        attn_out[(size_t)(b * TSEQ + q0w + mi * 16 + lg * 4 + r) * HIDDEN_C + h * HDIM + dt * 16 + lr] = f2bf(v);
      }
}

extern "C" void kernel_launch(void* const* d_in, const int* in_sizes, int n_in,
                              void* d_out, int out_size, void* d_ws, size_t ws_size,
                              hipStream_t stream) {
  const float* x  = (const float*)d_in[0];
  const float* Wq = (const float*)d_in[1];
  const float* Wk = (const float*)d_in[2];
  const float* Wv = (const float*)d_in[3];
  const float* Wo = (const float*)d_in[4];
  float* out = (float*)d_out;
  char* ws = (char*)d_ws;

  u16* xb    = (u16*)(ws);                          // 16 MiB
  u16* wqkvT = (u16*)(ws + (size_t)(16u << 20));    // 12 MiB  [3072][2048]
  u16* woT   = (u16*)(ws + (size_t)(28u << 20));    //  8 MiB  [2048][2048]
  u16* qkv   = (u16*)(ws + (size_t)(36u << 20));    // 24 MiB  [4096][3072]
  u16* vtb   = (u16*)(ws + (size_t)(60u << 20));    //  4 MiB  [2][4][128][2048]
  u16* attn  = (u16*)(ws + (size_t)(64u << 20));    // 16 MiB  [4096][2048]

  dim3 tb(32, 8);
  convert_x_kernel<<<(BTR * HIDDEN_C / 8) / 256, 256, 0, stream>>>(x, xb);
  transpose_w_kernel<<<dim3(HIDDEN_C / 32, HIDDEN_C / 32), tb, 0, stream>>>(Wq, wqkvT, HIDDEN_C, HIDDEN_C);
  transpose_w_kernel<<<dim3(512 / 32, HIDDEN_C / 32), tb, 0, stream>>>(Wk, wqkvT + (size_t)2048 * 2048, HIDDEN_C, 512);
  transpose_w_kernel<<<dim3(512 / 32, HIDDEN_C / 32), tb, 0, stream>>>(Wv, wqkvT + (size_t)2560 * 2048, HIDDEN_C, 512);
  transpose_w_kernel<<<dim3(HIDDEN_C / 32, HIDDEN_C / 32), tb, 0, stream>>>(Wo, woT, HIDDEN_C, HIDDEN_C);

  gemm_bt_kernel<u16><<<dim3(NQKV / 128, BTR / 128), 256, 0, stream>>>(xb, wqkvT, qkv, BTR, NQKV, HIDDEN_C);

  const float scale = 0.53033008588991f;  // 6/sqrt(128)
  rope_kernel<<<(BTR * NHEADS * 4) / 256, 256, 0, stream>>>(qkv, 0, 4, scale);
  rope_kernel<<<(BTR * NKV * 4) / 256, 256, 0, stream>>>(qkv, HIDDEN_C, 2, 1.0f);

  transpose_v_kernel<<<dim3(TSEQ / 32, HDIM / 32, BATCH * NKV), tb, 0, stream>>>(qkv, vtb);

  attn_kernel<<<dim3(TSEQ / 128, NHEADS, BATCH), 256, 0, stream>>>(qkv, vtb, attn);

  gemm_bt_kernel<float><<<dim3(HIDDEN_C / 128, BTR / 128), 256, 0, stream>>>(attn, woT, out, BTR, HIDDEN_C, HIDDEN_C);
}

// Round 5
// 264.183 us; speedup vs baseline: 1.9695x; 1.9695x over previous
//
#include <hip/hip_runtime.h>
#include <hip/hip_bf16.h>
#include <cstdint>
#include <cstddef>

typedef unsigned short u16;
typedef short s16x8 __attribute__((ext_vector_type(8)));
typedef float f32x4 __attribute__((ext_vector_type(4)));
typedef u16 u16x4 __attribute__((ext_vector_type(4)));

#define HIDDEN_C 2048
#define TSEQ 2048
#define BATCH 2
#define NHEADS 16
#define NKV 4
#define HDIM 128
#define NQKV 3072
#define BTR 4096  // BATCH*TSEQ

__device__ __forceinline__ float bf2f(u16 u) {
  union { uint32_t i; float f; } v; v.i = ((uint32_t)u) << 16; return v.f;
}
__device__ __forceinline__ u16 f2bf(float f) {
  union { float f; uint32_t i; } v; v.f = f;
  uint32_t r = v.i + 0x7fffu + ((v.i >> 16) & 1u);
  return (u16)(r >> 16);
}

#define AS1(p) ((__attribute__((address_space(1))) void*)(uintptr_t)(p))
#define AS3(p) ((__attribute__((address_space(3))) void*)(p))

// ---------------- fp32 -> bf16 convert (8 elems/thread) ----------------
__global__ void convert_x_kernel(const float* __restrict__ x, u16* __restrict__ xb) {
  int i = (blockIdx.x * blockDim.x + threadIdx.x) * 8;
  float4 a = *(const float4*)(x + i);
  float4 b = *(const float4*)(x + i + 4);
  uint4 o;
  o.x = (uint32_t)f2bf(a.x) | ((uint32_t)f2bf(a.y) << 16);
  o.y = (uint32_t)f2bf(a.z) | ((uint32_t)f2bf(a.w) << 16);
  o.z = (uint32_t)f2bf(b.x) | ((uint32_t)f2bf(b.y) << 16);
  o.w = (uint32_t)f2bf(b.z) | ((uint32_t)f2bf(b.w) << 16);
  *(uint4*)(xb + i) = o;
}

// ---------------- W [R][C] fp32 -> W^T [C][R] bf16 ----------------
__global__ void transpose_w_kernel(const float* __restrict__ in, u16* __restrict__ out,
                                   int R, int C) {
  __shared__ float tile[32][33];
  int r0 = blockIdx.y * 32, c0 = blockIdx.x * 32;
  int tx = threadIdx.x, ty = threadIdx.y;
  #pragma unroll
  for (int i = 0; i < 32; i += 8)
    tile[ty + i][tx] = in[(size_t)(r0 + ty + i) * C + c0 + tx];
  __syncthreads();
  #pragma unroll
  for (int i = 0; i < 32; i += 8)
    out[(size_t)(c0 + ty + i) * R + r0 + tx] = f2bf(tile[tx][ty + i]);
}

// ---------------- GEMM: C[M][N] = A[M][K] * BT[N][K]^T (bf16 in, OutT out) -------
template <typename OutT>
__global__ __launch_bounds__(256) void gemm_bt_kernel(const u16* __restrict__ A,
                                                      const u16* __restrict__ BT,
                                                      OutT* __restrict__ C,
                                                      int M, int N, int K) {
  __shared__ u16 As[128 * 32];
  __shared__ u16 Bs[128 * 32];
  const int tid = threadIdx.x;
  const int wave = tid >> 6, lane = tid & 63;
  const int lr = lane & 15, lg = lane >> 4;
  const int m0 = blockIdx.y * 128, n0 = blockIdx.x * 128;
  const int wr = wave >> 1, wc = wave & 1;
  f32x4 acc[4][4];
  #pragma unroll
  for (int a = 0; a < 4; ++a)
    #pragma unroll
    for (int b = 0; b < 4; ++b) acc[a][b] = (f32x4){0.f, 0.f, 0.f, 0.f};

  for (int k0 = 0; k0 < K; k0 += 32) {
    #pragma unroll
    for (int i = 0; i < 2; ++i) {
      int c = tid + i * 256;
      int row = c >> 2, col8 = (c & 3) * 8;
      const u16* gA = A + (size_t)(m0 + row) * K + k0 + col8;
      const u16* gB = BT + (size_t)(n0 + row) * K + k0 + col8;
      char* lA = (char*)As + ((size_t)(wave * 64 + i * 256)) * 16;
      char* lB = (char*)Bs + ((size_t)(wave * 64 + i * 256)) * 16;
      __builtin_amdgcn_global_load_lds(AS1(gA), AS3(lA), 16, 0, 0);
      __builtin_amdgcn_global_load_lds(AS1(gB), AS3(lB), 16, 0, 0);
    }
    __syncthreads();
    s16x8 af[4], bfr[4];
    #pragma unroll
    for (int mi = 0; mi < 4; ++mi)
      af[mi] = *(const s16x8*)(As + (wr * 64 + mi * 16 + lr) * 32 + lg * 8);
    #pragma unroll
    for (int ni = 0; ni < 4; ++ni)
      bfr[ni] = *(const s16x8*)(Bs + (wc * 64 + ni * 16 + lr) * 32 + lg * 8);
    #pragma unroll
    for (int mi = 0; mi < 4; ++mi)
      #pragma unroll
      for (int ni = 0; ni < 4; ++ni)
        acc[mi][ni] = __builtin_amdgcn_mfma_f32_16x16x32_bf16(af[mi], bfr[ni], acc[mi][ni], 0, 0, 0);
    __syncthreads();
  }
  #pragma unroll
  for (int mi = 0; mi < 4; ++mi) {
    int rowb = m0 + wr * 64 + mi * 16 + lg * 4;
    #pragma unroll
    for (int ni = 0; ni < 4; ++ni) {
      int col = n0 + wc * 64 + ni * 16 + lr;
      #pragma unroll
      for (int r = 0; r < 4; ++r) {
        float v = acc[mi][ni][r];
        if constexpr (sizeof(OutT) == 2) C[(size_t)(rowb + r) * N + col] = (OutT)f2bf(v);
        else                             C[(size_t)(rowb + r) * N + col] = v;
      }
    }
  }
}

// ---------------- RoPE (+optional scale), in-place on qkv ----------------
__global__ void rope_kernel(u16* __restrict__ base, int col_off, int head_shift, float scale) {
  int idx = blockIdx.x * blockDim.x + threadIdx.x;
  int quarter = idx & 3;
  int hidx = idx >> 2;
  int head = hidx & ((1 << head_shift) - 1);
  int bt = hidx >> head_shift;
  if (bt >= BTR) return;
  int t = bt & (TSEQ - 1);
  u16* p = base + (size_t)bt * NQKV + col_off + head * HDIM + quarter * 32;
  uint4 u[4];
  #pragma unroll
  for (int j = 0; j < 4; ++j) u[j] = ((const uint4*)p)[j];
  float v[32];
  #pragma unroll
  for (int j = 0; j < 4; ++j) {
    v[j*8+0] = bf2f((u16)(u[j].x & 0xffff)); v[j*8+1] = bf2f((u16)(u[j].x >> 16));
    v[j*8+2] = bf2f((u16)(u[j].y & 0xffff)); v[j*8+3] = bf2f((u16)(u[j].y >> 16));
    v[j*8+4] = bf2f((u16)(u[j].z & 0xffff)); v[j*8+5] = bf2f((u16)(u[j].z >> 16));
    v[j*8+6] = bf2f((u16)(u[j].w & 0xffff)); v[j*8+7] = bf2f((u16)(u[j].w >> 16));
  }
  if (quarter == 0) {
    #pragma unroll
    for (int i = 0; i < 16; ++i) {
      float f = powf(10000.f, -(float)i * (1.f / 16.f));
      float ang = (float)t * f;
      float s = sinf(ang), c = cosf(ang);
      float a = v[i], b = v[i + 16];
      v[i]      = a * c - b * s;
      v[i + 16] = b * c + a * s;
    }
  }
  #pragma unroll
  for (int i = 0; i < 32; ++i) v[i] *= scale;
  #pragma unroll
  for (int j = 0; j < 4; ++j) {
    u[j].x = (uint32_t)f2bf(v[j*8+0]) | ((uint32_t)f2bf(v[j*8+1]) << 16);
    u[j].y = (uint32_t)f2bf(v[j*8+2]) | ((uint32_t)f2bf(v[j*8+3]) << 16);
    u[j].z = (uint32_t)f2bf(v[j*8+4]) | ((uint32_t)f2bf(v[j*8+5]) << 16);
    u[j].w = (uint32_t)f2bf(v[j*8+6]) | ((uint32_t)f2bf(v[j*8+7]) << 16);
  }
  #pragma unroll
  for (int j = 0; j < 4; ++j) ((uint4*)p)[j] = u[j];
}

// ---------------- V [b][t][g][d] -> VT [b][g][d][t] ----------------
__global__ void transpose_v_kernel(const u16* __restrict__ qkv, u16* __restrict__ vt) {
  int bg = blockIdx.z;
  int b = bg >> 2, g = bg & 3;
  int t0 = blockIdx.x * 32, d0 = blockIdx.y * 32;
  __shared__ u16 tile[32][33];
  int tx = threadIdx.x, ty = threadIdx.y;
  #pragma unroll
  for (int i = 0; i < 32; i += 8)
    tile[ty + i][tx] = qkv[(size_t)(b * TSEQ + t0 + ty + i) * NQKV + 2560 + g * HDIM + d0 + tx];
  __syncthreads();
  #pragma unroll
  for (int i = 0; i < 32; i += 8)
    vt[((size_t)bg * HDIM + d0 + ty + i) * TSEQ + t0 + tx] = tile[tx][ty + i];
}

// ---------------- flash attention v5: swapped-QK^T, in-register softmax ------
// 4 waves x 32 Q-rows; KVBLK=64; K,V double-buffered in LDS (XOR swizzle via
// pre-swizzled source). S^T = mfma(K,Q): each lane owns one q-row along k ->
// softmax in-register (only 2 shfl per reduce); P packed to bf16 in-register,
// exchanged via 8 ds_write_b64 + 4 ds_read_b128; O^T = mfma(V^T, P^T).
__global__ __launch_bounds__(256, 2) void attn_kernel(const u16* __restrict__ qkv,
                                                      const u16* __restrict__ vt,
                                                      u16* __restrict__ attn_out) {
  __shared__ u16 K_lds[2][64][128];   // [buf][kpos][d]   32 KB
  __shared__ u16 V_lds[2][128][64];   // [buf][d][kpos]   32 KB
  __shared__ u16 P_lds[4][2][16][64]; // [wave][mi][q][k] 16 KB

  const int b = blockIdx.z, h = blockIdx.y, g = h >> 2;
  const int tid = threadIdx.x, w = tid >> 6, lane = tid & 63;
  const int lr = lane & 15, lg = lane >> 4;
  const int tile = (int)gridDim.x - 1 - (int)blockIdx.x;  // longest first
  const int q0 = tile * 128;
  const int q0w = q0 + w * 32;
  const int swz = (lr & 7) << 3;  // P swizzle key (elements)

  const u16* Qg = qkv + (size_t)b * TSEQ * NQKV + h * HDIM;
  const u16* Kg = qkv + (size_t)b * TSEQ * NQKV + HIDDEN_C + g * HDIM;
  const u16* Vg = vt + (size_t)(b * NKV + g) * HDIM * TSEQ;

  // Q fragments (B-operand): q-col = lr, d = kk*32 + lg*8..+7
  s16x8 aq[2][4];
  #pragma unroll
  for (int mi = 0; mi < 2; ++mi) {
    const u16* qrow = Qg + (size_t)(q0w + mi * 16 + lr) * NQKV + lg * 8;
    #pragma unroll
    for (int kk = 0; kk < 4; ++kk) aq[mi][kk] = *(const s16x8*)(qrow + kk * 32);
  }

  // O^T accumulators: col=q(lr), row = d_local = lg*4 + r
  f32x4 O[2][8];
  #pragma unroll
  for (int mi = 0; mi < 2; ++mi)
    #pragma unroll
    for (int dt = 0; dt < 8; ++dt) O[mi][dt] = (f32x4){0.f, 0.f, 0.f, 0.f};
  float m_r[2] = {-1e30f, -1e30f}, l_r[2] = {0.f, 0.f};

  auto STAGE = [&](int buf, int kb) {
    #pragma unroll
    for (int i = 0; i < 4; ++i) {          // K: 64 rows x 16 chunks of 16B
      int c = tid + i * 256;
      int row = c >> 4, slot = c & 15;
      int gslot = slot ^ (row & 7);
      const u16* src = Kg + (size_t)(kb + row) * NQKV + gslot * 8;
      char* dst = (char*)&K_lds[buf][0][0] + (size_t)c * 16;
      __builtin_amdgcn_global_load_lds(AS1(src), AS3(dst), 16, 0, 0);
    }
    #pragma unroll
    for (int i = 0; i < 4; ++i) {          // V: 128 rows(d) x 8 chunks of 16B
      int c = tid + i * 256;
      int row = c >> 3, slot = c & 7;
      int gslot = slot ^ (row & 7);
      const u16* src = Vg + (size_t)row * TSEQ + kb + gslot * 8;
      char* dst = (char*)&V_lds[buf][0][0] + (size_t)c * 16;
      __builtin_amdgcn_global_load_lds(AS1(src), AS3(dst), 16, 0, 0);
    }
  };

  const int nt = (q0 + 128) / 64;  // causal: k < q0+128
  STAGE(0, 0);
  asm volatile("s_waitcnt vmcnt(0)" ::: "memory");
  __syncthreads();

  for (int t = 0; t < nt; ++t) {
    const int kb = t * 64;
    const int cur = t & 1;
    if (t + 1 < nt) STAGE(cur ^ 1, kb + 64);

    if (kb <= q0w + 31) {
      // ---- QK^T (swapped): S^T[k_local, q] = mfma(A=K, B=Q) ----
      // lane: q = q0w + mi*16 + lr; k = kb + ni*16 + lg*4 + r
      f32x4 S[2][4];
      #pragma unroll
      for (int mi = 0; mi < 2; ++mi)
        #pragma unroll
        for (int ni = 0; ni < 4; ++ni) S[mi][ni] = (f32x4){0.f, 0.f, 0.f, 0.f};
      #pragma unroll
      for (int ni = 0; ni < 4; ++ni) {
        const u16* krow = &K_lds[cur][ni * 16 + lr][0];
        #pragma unroll
        for (int kk = 0; kk < 4; ++kk) {
          s16x8 bk = *(const s16x8*)(krow + ((kk * 32 + lg * 8) ^ swz));
          #pragma unroll
          for (int mi = 0; mi < 2; ++mi)
            S[mi][ni] = __builtin_amdgcn_mfma_f32_16x16x32_bf16(bk, aq[mi][kk], S[mi][ni], 0, 0, 0);
        }
      }
      // ---- causal mask: k > q -> -1e30 ----
      if (kb + 63 > q0w) {
        #pragma unroll
        for (int mi = 0; mi < 2; ++mi) {
          int qrow = q0w + mi * 16 + lr;
          #pragma unroll
          for (int ni = 0; ni < 4; ++ni) {
            int kbase = kb + ni * 16 + lg * 4;
            #pragma unroll
            for (int r = 0; r < 4; ++r)
              if (kbase + r > qrow) S[mi][ni][r] = -1e30f;
          }
        }
      }
      // ---- online softmax, in-register per q-row ----
      #pragma unroll
      for (int mi = 0; mi < 2; ++mi) {
        f32x4 mm01, mm;
        #pragma unroll
        for (int r = 0; r < 4; ++r) mm01[r] = fmaxf(S[mi][0][r], S[mi][1][r]);
        #pragma unroll
        for (int r = 0; r < 4; ++r) mm[r] = fmaxf(mm01[r], fmaxf(S[mi][2][r], S[mi][3][r]));
        float v = fmaxf(fmaxf(mm[0], mm[1]), fmaxf(mm[2], mm[3]));
        v = fmaxf(v, __shfl_xor(v, 16));
        v = fmaxf(v, __shfl_xor(v, 32));
        float mn = fmaxf(m_r[mi], v);
        float al = __expf(m_r[mi] - mn);
        m_r[mi] = mn;
        f32x4 psv = (f32x4){0.f, 0.f, 0.f, 0.f};
        #pragma unroll
        for (int ni = 0; ni < 4; ++ni)
          #pragma unroll
          for (int r = 0; r < 4; ++r) {
            float p = __expf(S[mi][ni][r] - mn);
            S[mi][ni][r] = p;
            psv[r] += p;
          }
        float ps = (psv[0] + psv[1]) + (psv[2] + psv[3]);
        ps += __shfl_xor(ps, 16);
        ps += __shfl_xor(ps, 32);
        l_r[mi] = l_r[mi] * al + ps;
        #pragma unroll
        for (int dt = 0; dt < 8; ++dt)
          #pragma unroll
          for (int r = 0; r < 4; ++r) O[mi][dt][r] *= al;
        // ---- pack P to bf16, write k-quad per ni (b64) ----
        u16* pw = &P_lds[w][mi][lr][0];
        #pragma unroll
        for (int ni = 0; ni < 4; ++ni) {
          u16x4 hq;
          #pragma unroll
          for (int r = 0; r < 4; ++r) hq[r] = f2bf(S[mi][ni][r]);
          *(u16x4*)(pw + ((ni * 16 + lg * 4) ^ swz)) = hq;
        }
      }
      asm volatile("s_waitcnt lgkmcnt(0)" ::: "memory");
      __builtin_amdgcn_sched_barrier(0);
      // ---- PV (swapped): O^T += mfma(A=V^T, B=P^T) ----
      s16x8 pa[2][2];
      #pragma unroll
      for (int mi = 0; mi < 2; ++mi) {
        const u16* prow = &P_lds[w][mi][lr][0];
        #pragma unroll
        for (int ks = 0; ks < 2; ++ks)
          pa[mi][ks] = *(const s16x8*)(prow + ((ks * 32 + lg * 8) ^ swz));
      }
      #pragma unroll
      for (int dt = 0; dt < 8; ++dt) {
        const u16* vrow = &V_lds[cur][dt * 16 + lr][0];
        #pragma unroll
        for (int ks = 0; ks < 2; ++ks) {
          s16x8 bv = *(const s16x8*)(vrow + ((ks * 32 + lg * 8) ^ swz));
          #pragma unroll
          for (int mi = 0; mi < 2; ++mi)
            O[mi][dt] = __builtin_amdgcn_mfma_f32_16x16x32_bf16(bv, pa[mi][ks], O[mi][dt], 0, 0, 0);
        }
      }
    }
    asm volatile("s_waitcnt vmcnt(0)" ::: "memory");
    __syncthreads();
  }

  // epilogue: O^T -> attn_out; q = q0w+mi*16+lr, d = dt*16+lg*4+r
  #pragma unroll
  for (int mi = 0; mi < 2; ++mi) {
    float invl = 1.f / l_r[mi];
    u16* orow = attn_out + (size_t)(b * TSEQ + q0w + mi * 16 + lr) * HIDDEN_C + h * HDIM + lg * 4;
    #pragma unroll
    for (int dt = 0; dt < 8; ++dt) {
      u16x4 o4;
      #pragma unroll
      for (int r = 0; r < 4; ++r) o4[r] = f2bf(O[mi][dt][r] * invl);
      *(u16x4*)(orow + dt * 16) = o4;
    }
  }
}

extern "C" void kernel_launch(void* const* d_in, const int* in_sizes, int n_in,
                              void* d_out, int out_size, void* d_ws, size_t ws_size,
                              hipStream_t stream) {
  const float* x  = (const float*)d_in[0];
  const float* Wq = (const float*)d_in[1];
  const float* Wk = (const float*)d_in[2];
  const float* Wv = (const float*)d_in[3];
  const float* Wo = (const float*)d_in[4];
  float* out = (float*)d_out;
  char* ws = (char*)d_ws;

  u16* xb    = (u16*)(ws);                          // 16 MiB
  u16* wqkvT = (u16*)(ws + (size_t)(16u << 20));    // 12 MiB  [3072][2048]
  u16* woT   = (u16*)(ws + (size_t)(28u << 20));    //  8 MiB  [2048][2048]
  u16* qkv   = (u16*)(ws + (size_t)(36u << 20));    // 24 MiB  [4096][3072]
  u16* vtb   = (u16*)(ws + (size_t)(60u << 20));    //  4 MiB  [2][4][128][2048]
  u16* attn  = (u16*)(ws + (size_t)(64u << 20));    // 16 MiB  [4096][2048]

  dim3 tb(32, 8);
  convert_x_kernel<<<(BTR * HIDDEN_C / 8) / 256, 256, 0, stream>>>(x, xb);
  transpose_w_kernel<<<dim3(HIDDEN_C / 32, HIDDEN_C / 32), tb, 0, stream>>>(Wq, wqkvT, HIDDEN_C, HIDDEN_C);
  transpose_w_kernel<<<dim3(512 / 32, HIDDEN_C / 32), tb, 0, stream>>>(Wk, wqkvT + (size_t)2048 * 2048, HIDDEN_C, 512);
  transpose_w_kernel<<<dim3(512 / 32, HIDDEN_C / 32), tb, 0, stream>>>(Wv, wqkvT + (size_t)2560 * 2048, HIDDEN_C, 512);
  transpose_w_kernel<<<dim3(HIDDEN_C / 32, HIDDEN_C / 32), tb, 0, stream>>>(Wo, woT, HIDDEN_C, HIDDEN_C);

  gemm_bt_kernel<u16><<<dim3(NQKV / 128, BTR / 128), 256, 0, stream>>>(xb, wqkvT, qkv, BTR, NQKV, HIDDEN_C);

  const float scale = 0.53033008588991f;  // 6/sqrt(128)
  rope_kernel<<<(BTR * NHEADS * 4) / 256, 256, 0, stream>>>(qkv, 0, 4, scale);
  rope_kernel<<<(BTR * NKV * 4) / 256, 256, 0, stream>>>(qkv, HIDDEN_C, 2, 1.0f);

  transpose_v_kernel<<<dim3(TSEQ / 32, HDIM / 32, BATCH * NKV), tb, 0, stream>>>(qkv, vtb);

  attn_kernel<<<dim3(TSEQ / 128, NHEADS, BATCH), 256, 0, stream>>>(qkv, vtb, attn);

  gemm_bt_kernel<float><<<dim3(HIDDEN_C / 128, BTR / 128), 256, 0, stream>>>(attn, woT, out, BTR, HIDDEN_C, HIDDEN_C);
}

// Round 6
// 247.722 us; speedup vs baseline: 2.1004x; 1.0665x over previous
//
#include <hip/hip_runtime.h>
#include <hip/hip_bf16.h>
#include <cstdint>
#include <cstddef>

typedef unsigned short u16;
typedef short s16x8 __attribute__((ext_vector_type(8)));
typedef float f32x4 __attribute__((ext_vector_type(4)));
typedef u16 u16x4 __attribute__((ext_vector_type(4)));

#define HIDDEN_C 2048
#define TSEQ 2048
#define BATCH 2
#define NHEADS 16
#define NKV 4
#define HDIM 128
#define NQKV 3072
#define BTR 4096  // BATCH*TSEQ

__device__ __forceinline__ float bf2f(u16 u) {
  union { uint32_t i; float f; } v; v.i = ((uint32_t)u) << 16; return v.f;
}
__device__ __forceinline__ u16 f2bf(float f) {
  union { float f; uint32_t i; } v; v.f = f;
  uint32_t r = v.i + 0x7fffu + ((v.i >> 16) & 1u);
  return (u16)(r >> 16);
}

#define AS1(p) ((__attribute__((address_space(1))) void*)(uintptr_t)(p))
#define AS3(p) ((__attribute__((address_space(3))) void*)(p))

// ---------------- fp32 -> bf16 convert (8 elems/thread) ----------------
__global__ void convert_x_kernel(const float* __restrict__ x, u16* __restrict__ xb) {
  int i = (blockIdx.x * blockDim.x + threadIdx.x) * 8;
  float4 a = *(const float4*)(x + i);
  float4 b = *(const float4*)(x + i + 4);
  uint4 o;
  o.x = (uint32_t)f2bf(a.x) | ((uint32_t)f2bf(a.y) << 16);
  o.y = (uint32_t)f2bf(a.z) | ((uint32_t)f2bf(a.w) << 16);
  o.z = (uint32_t)f2bf(b.x) | ((uint32_t)f2bf(b.y) << 16);
  o.w = (uint32_t)f2bf(b.z) | ((uint32_t)f2bf(b.w) << 16);
  *(uint4*)(xb + i) = o;
}

// ---------------- W [R][C] fp32 -> W^T [C][R] bf16 ----------------
__global__ void transpose_w_kernel(const float* __restrict__ in, u16* __restrict__ out,
                                   int R, int C) {
  __shared__ float tile[32][33];
  int r0 = blockIdx.y * 32, c0 = blockIdx.x * 32;
  int tx = threadIdx.x, ty = threadIdx.y;
  #pragma unroll
  for (int i = 0; i < 32; i += 8)
    tile[ty + i][tx] = in[(size_t)(r0 + ty + i) * C + c0 + tx];
  __syncthreads();
  #pragma unroll
  for (int i = 0; i < 32; i += 8)
    out[(size_t)(c0 + ty + i) * R + r0 + tx] = f2bf(tile[tx][ty + i]);
}

// ---------------- GEMM: C[M][N] = A[M][K] * BT[N][K]^T (bf16 in, OutT out) -------
template <typename OutT>
__global__ __launch_bounds__(256) void gemm_bt_kernel(const u16* __restrict__ A,
                                                      const u16* __restrict__ BT,
                                                      OutT* __restrict__ C,
                                                      int M, int N, int K) {
  __shared__ u16 As[128 * 32];
  __shared__ u16 Bs[128 * 32];
  const int tid = threadIdx.x;
  const int wave = tid >> 6, lane = tid & 63;
  const int lr = lane & 15, lg = lane >> 4;
  const int m0 = blockIdx.y * 128, n0 = blockIdx.x * 128;
  const int wr = wave >> 1, wc = wave & 1;
  f32x4 acc[4][4];
  #pragma unroll
  for (int a = 0; a < 4; ++a)
    #pragma unroll
    for (int b = 0; b < 4; ++b) acc[a][b] = (f32x4){0.f, 0.f, 0.f, 0.f};

  for (int k0 = 0; k0 < K; k0 += 32) {
    #pragma unroll
    for (int i = 0; i < 2; ++i) {
      int c = tid + i * 256;
      int row = c >> 2, col8 = (c & 3) * 8;
      const u16* gA = A + (size_t)(m0 + row) * K + k0 + col8;
      const u16* gB = BT + (size_t)(n0 + row) * K + k0 + col8;
      char* lA = (char*)As + ((size_t)(wave * 64 + i * 256)) * 16;
      char* lB = (char*)Bs + ((size_t)(wave * 64 + i * 256)) * 16;
      __builtin_amdgcn_global_load_lds(AS1(gA), AS3(lA), 16, 0, 0);
      __builtin_amdgcn_global_load_lds(AS1(gB), AS3(lB), 16, 0, 0);
    }
    __syncthreads();
    s16x8 af[4], bfr[4];
    #pragma unroll
    for (int mi = 0; mi < 4; ++mi)
      af[mi] = *(const s16x8*)(As + (wr * 64 + mi * 16 + lr) * 32 + lg * 8);
    #pragma unroll
    for (int ni = 0; ni < 4; ++ni)
      bfr[ni] = *(const s16x8*)(Bs + (wc * 64 + ni * 16 + lr) * 32 + lg * 8);
    #pragma unroll
    for (int mi = 0; mi < 4; ++mi)
      #pragma unroll
      for (int ni = 0; ni < 4; ++ni)
        acc[mi][ni] = __builtin_amdgcn_mfma_f32_16x16x32_bf16(af[mi], bfr[ni], acc[mi][ni], 0, 0, 0);
    __syncthreads();
  }
  #pragma unroll
  for (int mi = 0; mi < 4; ++mi) {
    int rowb = m0 + wr * 64 + mi * 16 + lg * 4;
    #pragma unroll
    for (int ni = 0; ni < 4; ++ni) {
      int col = n0 + wc * 64 + ni * 16 + lr;
      #pragma unroll
      for (int r = 0; r < 4; ++r) {
        float v = acc[mi][ni][r];
        if constexpr (sizeof(OutT) == 2) C[(size_t)(rowb + r) * N + col] = (OutT)f2bf(v);
        else                             C[(size_t)(rowb + r) * N + col] = v;
      }
    }
  }
}

// ---------------- RoPE (+optional scale), in-place on qkv ----------------
__global__ void rope_kernel(u16* __restrict__ base, int col_off, int head_shift, float scale) {
  int idx = blockIdx.x * blockDim.x + threadIdx.x;
  int quarter = idx & 3;
  int hidx = idx >> 2;
  int head = hidx & ((1 << head_shift) - 1);
  int bt = hidx >> head_shift;
  if (bt >= BTR) return;
  int t = bt & (TSEQ - 1);
  u16* p = base + (size_t)bt * NQKV + col_off + head * HDIM + quarter * 32;
  uint4 u[4];
  #pragma unroll
  for (int j = 0; j < 4; ++j) u[j] = ((const uint4*)p)[j];
  float v[32];
  #pragma unroll
  for (int j = 0; j < 4; ++j) {
    v[j*8+0] = bf2f((u16)(u[j].x & 0xffff)); v[j*8+1] = bf2f((u16)(u[j].x >> 16));
    v[j*8+2] = bf2f((u16)(u[j].y & 0xffff)); v[j*8+3] = bf2f((u16)(u[j].y >> 16));
    v[j*8+4] = bf2f((u16)(u[j].z & 0xffff)); v[j*8+5] = bf2f((u16)(u[j].z >> 16));
    v[j*8+6] = bf2f((u16)(u[j].w & 0xffff)); v[j*8+7] = bf2f((u16)(u[j].w >> 16));
  }
  if (quarter == 0) {
    #pragma unroll
    for (int i = 0; i < 16; ++i) {
      float f = powf(10000.f, -(float)i * (1.f / 16.f));
      float ang = (float)t * f;
      float s = sinf(ang), c = cosf(ang);
      float a = v[i], b = v[i + 16];
      v[i]      = a * c - b * s;
      v[i + 16] = b * c + a * s;
    }
  }
  #pragma unroll
  for (int i = 0; i < 32; ++i) v[i] *= scale;
  #pragma unroll
  for (int j = 0; j < 4; ++j) {
    u[j].x = (uint32_t)f2bf(v[j*8+0]) | ((uint32_t)f2bf(v[j*8+1]) << 16);
    u[j].y = (uint32_t)f2bf(v[j*8+2]) | ((uint32_t)f2bf(v[j*8+3]) << 16);
    u[j].z = (uint32_t)f2bf(v[j*8+4]) | ((uint32_t)f2bf(v[j*8+5]) << 16);
    u[j].w = (uint32_t)f2bf(v[j*8+6]) | ((uint32_t)f2bf(v[j*8+7]) << 16);
  }
  #pragma unroll
  for (int j = 0; j < 4; ++j) ((uint4*)p)[j] = u[j];
}

// ---------------- V [b][t][g][d] -> VT [b][g][d][t] ----------------
__global__ void transpose_v_kernel(const u16* __restrict__ qkv, u16* __restrict__ vt) {
  int bg = blockIdx.z;
  int b = bg >> 2, g = bg & 3;
  int t0 = blockIdx.x * 32, d0 = blockIdx.y * 32;
  __shared__ u16 tile[32][33];
  int tx = threadIdx.x, ty = threadIdx.y;
  #pragma unroll
  for (int i = 0; i < 32; i += 8)
    tile[ty + i][tx] = qkv[(size_t)(b * TSEQ + t0 + ty + i) * NQKV + 2560 + g * HDIM + d0 + tx];
  __syncthreads();
  #pragma unroll
  for (int i = 0; i < 32; i += 8)
    vt[((size_t)bg * HDIM + d0 + ty + i) * TSEQ + t0 + tx] = tile[tx][ty + i];
}

// ---------------- flash attention v6: swapped-QK^T + complementary pairing ---
// 1D grid of 512 blocks: idx<256 -> tiles 15..8, idx>=256 -> tiles 0..7 so the
// two blocks round-robin-assigned to each CU (i, i+256) have tile sums = 15
// (iters sum = 36) -> balanced makespan and both blocks stay active.
__global__ __launch_bounds__(256, 2) void attn_kernel(const u16* __restrict__ qkv,
                                                      const u16* __restrict__ vt,
                                                      u16* __restrict__ attn_out) {
  __shared__ u16 K_lds[2][64][128];   // [buf][kpos][d]   32 KB
  __shared__ u16 V_lds[2][128][64];   // [buf][d][kpos]   32 KB
  __shared__ u16 P_lds[4][2][16][64]; // [wave][mi][q][k] 16 KB

  const int idx = blockIdx.x;
  const int h = idx & 15, b = (idx >> 4) & 1, g = h >> 2;
  const int j = (idx >> 5) & 7;
  const int tile = (idx >> 8) ? j : 15 - j;   // complementary pairing
  const int tid = threadIdx.x, w = tid >> 6, lane = tid & 63;
  const int lr = lane & 15, lg = lane >> 4;
  const int q0 = tile * 128;
  const int q0w = q0 + w * 32;
  const int swz = (lr & 7) << 3;  // P swizzle key (elements)

  const u16* Qg = qkv + (size_t)b * TSEQ * NQKV + h * HDIM;
  const u16* Kg = qkv + (size_t)b * TSEQ * NQKV + HIDDEN_C + g * HDIM;
  const u16* Vg = vt + (size_t)(b * NKV + g) * HDIM * TSEQ;

  // Q fragments (B-operand): q-col = lr, d = kk*32 + lg*8..+7
  s16x8 aq[2][4];
  #pragma unroll
  for (int mi = 0; mi < 2; ++mi) {
    const u16* qrow = Qg + (size_t)(q0w + mi * 16 + lr) * NQKV + lg * 8;
    #pragma unroll
    for (int kk = 0; kk < 4; ++kk) aq[mi][kk] = *(const s16x8*)(qrow + kk * 32);
  }

  // O^T accumulators: col=q(lr), row = d_local = lg*4 + r
  f32x4 O[2][8];
  #pragma unroll
  for (int mi = 0; mi < 2; ++mi)
    #pragma unroll
    for (int dt = 0; dt < 8; ++dt) O[mi][dt] = (f32x4){0.f, 0.f, 0.f, 0.f};
  float m_r[2] = {-1e30f, -1e30f}, l_r[2] = {0.f, 0.f};

  auto STAGE = [&](int buf, int kb) {
    #pragma unroll
    for (int i = 0; i < 4; ++i) {          // K: 64 rows x 16 chunks of 16B
      int c = tid + i * 256;
      int row = c >> 4, slot = c & 15;
      int gslot = slot ^ (row & 7);
      const u16* src = Kg + (size_t)(kb + row) * NQKV + gslot * 8;
      char* dst = (char*)&K_lds[buf][0][0] + (size_t)c * 16;
      __builtin_amdgcn_global_load_lds(AS1(src), AS3(dst), 16, 0, 0);
    }
    #pragma unroll
    for (int i = 0; i < 4; ++i) {          // V: 128 rows(d) x 8 chunks of 16B
      int c = tid + i * 256;
      int row = c >> 3, slot = c & 7;
      int gslot = slot ^ (row & 7);
      const u16* src = Vg + (size_t)row * TSEQ + kb + gslot * 8;
      char* dst = (char*)&V_lds[buf][0][0] + (size_t)c * 16;
      __builtin_amdgcn_global_load_lds(AS1(src), AS3(dst), 16, 0, 0);
    }
  };

  const int nt = (q0 + 128) / 64;  // causal: k < q0+128
  STAGE(0, 0);
  asm volatile("s_waitcnt vmcnt(0)" ::: "memory");
  __syncthreads();

  for (int t = 0; t < nt; ++t) {
    const int kb = t * 64;
    const int cur = t & 1;
    if (t + 1 < nt) STAGE(cur ^ 1, kb + 64);

    if (kb <= q0w + 31) {
      // ---- QK^T (swapped): S^T[k_local, q] = mfma(A=K, B=Q) ----
      f32x4 S[2][4];
      #pragma unroll
      for (int mi = 0; mi < 2; ++mi)
        #pragma unroll
        for (int ni = 0; ni < 4; ++ni) S[mi][ni] = (f32x4){0.f, 0.f, 0.f, 0.f};
      __builtin_amdgcn_s_setprio(1);
      #pragma unroll
      for (int ni = 0; ni < 4; ++ni) {
        const u16* krow = &K_lds[cur][ni * 16 + lr][0];
        #pragma unroll
        for (int kk = 0; kk < 4; ++kk) {
          s16x8 bk = *(const s16x8*)(krow + ((kk * 32 + lg * 8) ^ swz));
          #pragma unroll
          for (int mi = 0; mi < 2; ++mi)
            S[mi][ni] = __builtin_amdgcn_mfma_f32_16x16x32_bf16(bk, aq[mi][kk], S[mi][ni], 0, 0, 0);
        }
      }
      __builtin_amdgcn_s_setprio(0);
      // ---- causal mask: k > q -> -1e30 ----
      if (kb + 63 > q0w) {
        #pragma unroll
        for (int mi = 0; mi < 2; ++mi) {
          int qrow = q0w + mi * 16 + lr;
          #pragma unroll
          for (int ni = 0; ni < 4; ++ni) {
            int kbase = kb + ni * 16 + lg * 4;
            #pragma unroll
            for (int r = 0; r < 4; ++r)
              if (kbase + r > qrow) S[mi][ni][r] = -1e30f;
          }
        }
      }
      // ---- online softmax, in-register per q-row ----
      #pragma unroll
      for (int mi = 0; mi < 2; ++mi) {
        f32x4 mm01, mm;
        #pragma unroll
        for (int r = 0; r < 4; ++r) mm01[r] = fmaxf(S[mi][0][r], S[mi][1][r]);
        #pragma unroll
        for (int r = 0; r < 4; ++r) mm[r] = fmaxf(mm01[r], fmaxf(S[mi][2][r], S[mi][3][r]));
        float v = fmaxf(fmaxf(mm[0], mm[1]), fmaxf(mm[2], mm[3]));
        v = fmaxf(v, __shfl_xor(v, 16));
        v = fmaxf(v, __shfl_xor(v, 32));
        float mn = fmaxf(m_r[mi], v);
        float al = __expf(m_r[mi] - mn);
        m_r[mi] = mn;
        f32x4 psv = (f32x4){0.f, 0.f, 0.f, 0.f};
        #pragma unroll
        for (int ni = 0; ni < 4; ++ni)
          #pragma unroll
          for (int r = 0; r < 4; ++r) {
            float p = __expf(S[mi][ni][r] - mn);
            S[mi][ni][r] = p;
            psv[r] += p;
          }
        float ps = (psv[0] + psv[1]) + (psv[2] + psv[3]);
        ps += __shfl_xor(ps, 16);
        ps += __shfl_xor(ps, 32);
        l_r[mi] = l_r[mi] * al + ps;
        #pragma unroll
        for (int dt = 0; dt < 8; ++dt)
          #pragma unroll
          for (int r = 0; r < 4; ++r) O[mi][dt][r] *= al;
        // ---- pack P to bf16, write k-quad per ni (b64) ----
        u16* pw = &P_lds[w][mi][lr][0];
        #pragma unroll
        for (int ni = 0; ni < 4; ++ni) {
          u16x4 hq;
          #pragma unroll
          for (int r = 0; r < 4; ++r) hq[r] = f2bf(S[mi][ni][r]);
          *(u16x4*)(pw + ((ni * 16 + lg * 4) ^ swz)) = hq;
        }
      }
      asm volatile("s_waitcnt lgkmcnt(0)" ::: "memory");
      __builtin_amdgcn_sched_barrier(0);
      // ---- PV (swapped): O^T += mfma(A=V^T, B=P^T) ----
      s16x8 pa[2][2];
      #pragma unroll
      for (int mi = 0; mi < 2; ++mi) {
        const u16* prow = &P_lds[w][mi][lr][0];
        #pragma unroll
        for (int ks = 0; ks < 2; ++ks)
          pa[mi][ks] = *(const s16x8*)(prow + ((ks * 32 + lg * 8) ^ swz));
      }
      __builtin_amdgcn_s_setprio(1);
      #pragma unroll
      for (int dt = 0; dt < 8; ++dt) {
        const u16* vrow = &V_lds[cur][dt * 16 + lr][0];
        #pragma unroll
        for (int ks = 0; ks < 2; ++ks) {
          s16x8 bv = *(const s16x8*)(vrow + ((ks * 32 + lg * 8) ^ swz));
          #pragma unroll
          for (int mi = 0; mi < 2; ++mi)
            O[mi][dt] = __builtin_amdgcn_mfma_f32_16x16x32_bf16(bv, pa[mi][ks], O[mi][dt], 0, 0, 0);
        }
      }
      __builtin_amdgcn_s_setprio(0);
    }
    asm volatile("s_waitcnt vmcnt(0)" ::: "memory");
    __syncthreads();
  }

  // epilogue: O^T -> attn_out; q = q0w+mi*16+lr, d = dt*16+lg*4+r
  #pragma unroll
  for (int mi = 0; mi < 2; ++mi) {
    float invl = 1.f / l_r[mi];
    u16* orow = attn_out + (size_t)(b * TSEQ + q0w + mi * 16 + lr) * HIDDEN_C + h * HDIM + lg * 4;
    #pragma unroll
    for (int dt = 0; dt < 8; ++dt) {
      u16x4 o4;
      #pragma unroll
      for (int r = 0; r < 4; ++r) o4[r] = f2bf(O[mi][dt][r] * invl);
      *(u16x4*)(orow + dt * 16) = o4;
    }
  }
}

extern "C" void kernel_launch(void* const* d_in, const int* in_sizes, int n_in,
                              void* d_out, int out_size, void* d_ws, size_t ws_size,
                              hipStream_t stream) {
  const float* x  = (const float*)d_in[0];
  const float* Wq = (const float*)d_in[1];
  const float* Wk = (const float*)d_in[2];
  const float* Wv = (const float*)d_in[3];
  const float* Wo = (const float*)d_in[4];
  float* out = (float*)d_out;
  char* ws = (char*)d_ws;

  u16* xb    = (u16*)(ws);                          // 16 MiB
  u16* wqkvT = (u16*)(ws + (size_t)(16u << 20));    // 12 MiB  [3072][2048]
  u16* woT   = (u16*)(ws + (size_t)(28u << 20));    //  8 MiB  [2048][2048]
  u16* qkv   = (u16*)(ws + (size_t)(36u << 20));    // 24 MiB  [4096][3072]
  u16* vtb   = (u16*)(ws + (size_t)(60u << 20));    //  4 MiB  [2][4][128][2048]
  u16* attn  = (u16*)(ws + (size_t)(64u << 20));    // 16 MiB  [4096][2048]

  dim3 tb(32, 8);
  convert_x_kernel<<<(BTR * HIDDEN_C / 8) / 256, 256, 0, stream>>>(x, xb);
  transpose_w_kernel<<<dim3(HIDDEN_C / 32, HIDDEN_C / 32), tb, 0, stream>>>(Wq, wqkvT, HIDDEN_C, HIDDEN_C);
  transpose_w_kernel<<<dim3(512 / 32, HIDDEN_C / 32), tb, 0, stream>>>(Wk, wqkvT + (size_t)2048 * 2048, HIDDEN_C, 512);
  transpose_w_kernel<<<dim3(512 / 32, HIDDEN_C / 32), tb, 0, stream>>>(Wv, wqkvT + (size_t)2560 * 2048, HIDDEN_C, 512);
  transpose_w_kernel<<<dim3(HIDDEN_C / 32, HIDDEN_C / 32), tb, 0, stream>>>(Wo, woT, HIDDEN_C, HIDDEN_C);

  gemm_bt_kernel<u16><<<dim3(NQKV / 128, BTR / 128), 256, 0, stream>>>(xb, wqkvT, qkv, BTR, NQKV, HIDDEN_C);

  const float scale = 0.53033008588991f;  // 6/sqrt(128)
  rope_kernel<<<(BTR * NHEADS * 4) / 256, 256, 0, stream>>>(qkv, 0, 4, scale);
  rope_kernel<<<(BTR * NKV * 4) / 256, 256, 0, stream>>>(qkv, HIDDEN_C, 2, 1.0f);

  transpose_v_kernel<<<dim3(TSEQ / 32, HDIM / 32, BATCH * NKV), tb, 0, stream>>>(qkv, vtb);

  attn_kernel<<<512, 256, 0, stream>>>(qkv, vtb, attn);

  gemm_bt_kernel<float><<<dim3(HIDDEN_C / 128, BTR / 128), 256, 0, stream>>>(attn, woT, out, BTR, HIDDEN_C, HIDDEN_C);
}

// Round 8
// 246.371 us; speedup vs baseline: 2.1119x; 1.0055x over previous
//
#include <hip/hip_runtime.h>
#include <hip/hip_bf16.h>
#include <cstdint>
#include <cstddef>

typedef unsigned short u16;
typedef short s16x8 __attribute__((ext_vector_type(8)));
typedef float f32x4 __attribute__((ext_vector_type(4)));
typedef float f32x16 __attribute__((ext_vector_type(16)));
typedef u16 u16x4 __attribute__((ext_vector_type(4)));

#define HIDDEN_C 2048
#define TSEQ 2048
#define BATCH 2
#define NHEADS 16
#define NKV 4
#define HDIM 128
#define NQKV 3072
#define BTR 4096  // BATCH*TSEQ

__device__ __forceinline__ float bf2f(u16 u) {
  union { uint32_t i; float f; } v; v.i = ((uint32_t)u) << 16; return v.f;
}
__device__ __forceinline__ u16 f2bf(float f) {
  union { float f; uint32_t i; } v; v.f = f;
  uint32_t r = v.i + 0x7fffu + ((v.i >> 16) & 1u);
  return (u16)(r >> 16);
}

#define AS1(p) ((__attribute__((address_space(1))) void*)(uintptr_t)(p))
#define AS3(p) ((__attribute__((address_space(3))) void*)(p))

// ---------------- fp32 -> bf16 convert (8 elems/thread) ----------------
__global__ void convert_x_kernel(const float* __restrict__ x, u16* __restrict__ xb) {
  int i = (blockIdx.x * blockDim.x + threadIdx.x) * 8;
  float4 a = *(const float4*)(x + i);
  float4 b = *(const float4*)(x + i + 4);
  uint4 o;
  o.x = (uint32_t)f2bf(a.x) | ((uint32_t)f2bf(a.y) << 16);
  o.y = (uint32_t)f2bf(a.z) | ((uint32_t)f2bf(a.w) << 16);
  o.z = (uint32_t)f2bf(b.x) | ((uint32_t)f2bf(b.y) << 16);
  o.w = (uint32_t)f2bf(b.z) | ((uint32_t)f2bf(b.w) << 16);
  *(uint4*)(xb + i) = o;
}

// ---------------- W [R][C] fp32 -> W^T [C][R] bf16 ----------------
__global__ void transpose_w_kernel(const float* __restrict__ in, u16* __restrict__ out,
                                   int R, int C) {
  __shared__ float tile[32][33];
  int r0 = blockIdx.y * 32, c0 = blockIdx.x * 32;
  int tx = threadIdx.x, ty = threadIdx.y;
  #pragma unroll
  for (int i = 0; i < 32; i += 8)
    tile[ty + i][tx] = in[(size_t)(r0 + ty + i) * C + c0 + tx];
  __syncthreads();
  #pragma unroll
  for (int i = 0; i < 32; i += 8)
    out[(size_t)(c0 + ty + i) * R + r0 + tx] = f2bf(tile[tx][ty + i]);
}

// ---------------- GEMM: C[M][N] = A[M][K] * BT[N][K]^T (bf16 in, OutT out) -------
template <typename OutT>
__global__ __launch_bounds__(256) void gemm_bt_kernel(const u16* __restrict__ A,
                                                      const u16* __restrict__ BT,
                                                      OutT* __restrict__ C,
                                                      int M, int N, int K) {
  __shared__ u16 As[128 * 32];
  __shared__ u16 Bs[128 * 32];
  const int tid = threadIdx.x;
  const int wave = tid >> 6, lane = tid & 63;
  const int lr = lane & 15, lg = lane >> 4;
  const int m0 = blockIdx.y * 128, n0 = blockIdx.x * 128;
  const int wr = wave >> 1, wc = wave & 1;
  f32x4 acc[4][4];
  #pragma unroll
  for (int a = 0; a < 4; ++a)
    #pragma unroll
    for (int b = 0; b < 4; ++b) acc[a][b] = (f32x4){0.f, 0.f, 0.f, 0.f};

  for (int k0 = 0; k0 < K; k0 += 32) {
    #pragma unroll
    for (int i = 0; i < 2; ++i) {
      int c = tid + i * 256;
      int row = c >> 2, col8 = (c & 3) * 8;
      const u16* gA = A + (size_t)(m0 + row) * K + k0 + col8;
      const u16* gB = BT + (size_t)(n0 + row) * K + k0 + col8;
      char* lA = (char*)As + ((size_t)(wave * 64 + i * 256)) * 16;
      char* lB = (char*)Bs + ((size_t)(wave * 64 + i * 256)) * 16;
      __builtin_amdgcn_global_load_lds(AS1(gA), AS3(lA), 16, 0, 0);
      __builtin_amdgcn_global_load_lds(AS1(gB), AS3(lB), 16, 0, 0);
    }
    __syncthreads();
    s16x8 af[4], bfr[4];
    #pragma unroll
    for (int mi = 0; mi < 4; ++mi)
      af[mi] = *(const s16x8*)(As + (wr * 64 + mi * 16 + lr) * 32 + lg * 8);
    #pragma unroll
    for (int ni = 0; ni < 4; ++ni)
      bfr[ni] = *(const s16x8*)(Bs + (wc * 64 + ni * 16 + lr) * 32 + lg * 8);
    #pragma unroll
    for (int mi = 0; mi < 4; ++mi)
      #pragma unroll
      for (int ni = 0; ni < 4; ++ni)
        acc[mi][ni] = __builtin_amdgcn_mfma_f32_16x16x32_bf16(af[mi], bfr[ni], acc[mi][ni], 0, 0, 0);
    __syncthreads();
  }
  #pragma unroll
  for (int mi = 0; mi < 4; ++mi) {
    int rowb = m0 + wr * 64 + mi * 16 + lg * 4;
    #pragma unroll
    for (int ni = 0; ni < 4; ++ni) {
      int col = n0 + wc * 64 + ni * 16 + lr;
      #pragma unroll
      for (int r = 0; r < 4; ++r) {
        float v = acc[mi][ni][r];
        if constexpr (sizeof(OutT) == 2) C[(size_t)(rowb + r) * N + col] = (OutT)f2bf(v);
        else                             C[(size_t)(rowb + r) * N + col] = v;
      }
    }
  }
}

// ---------------- RoPE (+optional scale), in-place on qkv ----------------
__global__ void rope_kernel(u16* __restrict__ base, int col_off, int head_shift, float scale) {
  int idx = blockIdx.x * blockDim.x + threadIdx.x;
  int quarter = idx & 3;
  int hidx = idx >> 2;
  int head = hidx & ((1 << head_shift) - 1);
  int bt = hidx >> head_shift;
  if (bt >= BTR) return;
  int t = bt & (TSEQ - 1);
  u16* p = base + (size_t)bt * NQKV + col_off + head * HDIM + quarter * 32;
  uint4 u[4];
  #pragma unroll
  for (int j = 0; j < 4; ++j) u[j] = ((const uint4*)p)[j];
  float v[32];
  #pragma unroll
  for (int j = 0; j < 4; ++j) {
    v[j*8+0] = bf2f((u16)(u[j].x & 0xffff)); v[j*8+1] = bf2f((u16)(u[j].x >> 16));
    v[j*8+2] = bf2f((u16)(u[j].y & 0xffff)); v[j*8+3] = bf2f((u16)(u[j].y >> 16));
    v[j*8+4] = bf2f((u16)(u[j].z & 0xffff)); v[j*8+5] = bf2f((u16)(u[j].z >> 16));
    v[j*8+6] = bf2f((u16)(u[j].w & 0xffff)); v[j*8+7] = bf2f((u16)(u[j].w >> 16));
  }
  if (quarter == 0) {
    #pragma unroll
    for (int i = 0; i < 16; ++i) {
      float f = powf(10000.f, -(float)i * (1.f / 16.f));
      float ang = (float)t * f;
      float s = sinf(ang), c = cosf(ang);
      float a = v[i], b = v[i + 16];
      v[i]      = a * c - b * s;
      v[i + 16] = b * c + a * s;
    }
  }
  #pragma unroll
  for (int i = 0; i < 32; ++i) v[i] *= scale;
  #pragma unroll
  for (int j = 0; j < 4; ++j) {
    u[j].x = (uint32_t)f2bf(v[j*8+0]) | ((uint32_t)f2bf(v[j*8+1]) << 16);
    u[j].y = (uint32_t)f2bf(v[j*8+2]) | ((uint32_t)f2bf(v[j*8+3]) << 16);
    u[j].z = (uint32_t)f2bf(v[j*8+4]) | ((uint32_t)f2bf(v[j*8+5]) << 16);
    u[j].w = (uint32_t)f2bf(v[j*8+6]) | ((uint32_t)f2bf(v[j*8+7]) << 16);
  }
  #pragma unroll
  for (int j = 0; j < 4; ++j) ((uint4*)p)[j] = u[j];
}

// ---------------- V [b][t][g][d] -> VT [b][g][d][t] ----------------
__global__ void transpose_v_kernel(const u16* __restrict__ qkv, u16* __restrict__ vt) {
  int bg = blockIdx.z;
  int b = bg >> 2, g = bg & 3;
  int t0 = blockIdx.x * 32, d0 = blockIdx.y * 32;
  __shared__ u16 tile[32][33];
  int tx = threadIdx.x, ty = threadIdx.y;
  #pragma unroll
  for (int i = 0; i < 32; i += 8)
    tile[ty + i][tx] = qkv[(size_t)(b * TSEQ + t0 + ty + i) * NQKV + 2560 + g * HDIM + d0 + tx];
  __syncthreads();
  #pragma unroll
  for (int i = 0; i < 32; i += 8)
    vt[((size_t)bg * HDIM + d0 + ty + i) * TSEQ + t0 + tx] = tile[tx][ty + i];
}

// ---------------- flash attention v8: 32x32 swapped MFMA, LDS P path --------
// 4 waves x 32 Q-rows; KVBLK=64; K,V LDS-dbuf (XOR swizzle, pre-swizzled src);
// S^T = mfma32(K,Q): lane owns full q-row (32 k per kh, hf-split) -> softmax
// in-register trees + 2x shfl_xor(32). P via proven LDS path (swizzled u16x4
// writes + ds_read_b128). O^T = mfma32(V^T, P^T). 80 KB LDS, 2 blocks/CU.
__global__ __launch_bounds__(256, 2) void attn_kernel(const u16* __restrict__ qkv,
                                                      const u16* __restrict__ vt,
                                                      u16* __restrict__ attn_out) {
  __shared__ u16 K_lds[2][64][128];   // [buf][k][d]   32 KB
  __shared__ u16 V_lds[2][128][64];   // [buf][d][k]   32 KB
  __shared__ u16 P_lds[4][32][64];    // [wave][q][k]  16 KB

  const int idx = blockIdx.x;
  const int h = idx & 15, b = (idx >> 4) & 1, g = h >> 2;
  const int jb = (idx >> 5) & 7;
  const int tile = (idx >> 8) ? jb : 15 - jb;   // complementary pairing
  const int tid = threadIdx.x, w = tid >> 6, lane = tid & 63;
  const int lq = lane & 31;        // q (and k/d row) index within 32
  const int hf = lane >> 5;        // lane half
  const int q0 = tile * 128;
  const int q0w = q0 + w * 32;
  const int swz = (lane & 7) << 3; // element-XOR for K/V reads (row = lq)
  const int pswz = lq & 7;         // P slot swizzle key

  const u16* Qg = qkv + (size_t)b * TSEQ * NQKV + h * HDIM;
  const u16* Kg = qkv + (size_t)b * TSEQ * NQKV + HIDDEN_C + g * HDIM;
  const u16* Vg = vt + (size_t)(b * NKV + g) * HDIM * TSEQ;

  // Q frags (B-operand): col q = lq, slot d = ds*16 + hf*8 + j
  s16x8 aq[8];
  {
    const u16* qrow = Qg + (size_t)(q0w + lq) * NQKV + hf * 8;
    #pragma unroll
    for (int ds = 0; ds < 8; ++ds) aq[ds] = *(const s16x8*)(qrow + ds * 16);
  }

  // O^T accumulators: col q = lq, row d = dt*32 + (r&3) + 8*(r>>2) + 4*hf
  f32x16 O[4];
  #pragma unroll
  for (int dt = 0; dt < 4; ++dt)
    #pragma unroll
    for (int r = 0; r < 16; ++r) O[dt][r] = 0.f;
  float m_r = -1e30f, l_r = 0.f;

  auto STAGE = [&](int buf, int kb) {
    #pragma unroll
    for (int i = 0; i < 4; ++i) {          // K: 64 rows x 16 chunks of 16B
      int c = tid + i * 256;
      int row = c >> 4, slot = c & 15;
      int gslot = slot ^ (row & 7);
      const u16* src = Kg + (size_t)(kb + row) * NQKV + gslot * 8;
      char* dst = (char*)&K_lds[buf][0][0] + (size_t)c * 16;
      __builtin_amdgcn_global_load_lds(AS1(src), AS3(dst), 16, 0, 0);
    }
    #pragma unroll
    for (int i = 0; i < 4; ++i) {          // V: 128 rows(d) x 8 chunks of 16B
      int c = tid + i * 256;
      int row = c >> 3, slot = c & 7;
      int gslot = slot ^ (row & 7);
      const u16* src = Vg + (size_t)row * TSEQ + kb + gslot * 8;
      char* dst = (char*)&V_lds[buf][0][0] + (size_t)c * 16;
      __builtin_amdgcn_global_load_lds(AS1(src), AS3(dst), 16, 0, 0);
    }
  };

  const int nt = (q0 + 128) / 64;  // causal: k < q0+128
  STAGE(0, 0);
  asm volatile("s_waitcnt vmcnt(0)" ::: "memory");
  __syncthreads();

  for (int t = 0; t < nt; ++t) {
    const int kb = t * 64;
    const int cur = t & 1;
    if (t + 1 < nt) STAGE(cur ^ 1, kb + 64);

    if (kb <= q0w + 31) {
      // ---- QK^T (swapped, 32x32x16): S^T[k][q] per k-half ----
      f32x16 S[2];
      #pragma unroll
      for (int kh = 0; kh < 2; ++kh)
        #pragma unroll
        for (int r = 0; r < 16; ++r) S[kh][r] = 0.f;
      __builtin_amdgcn_s_setprio(1);
      #pragma unroll
      for (int kh = 0; kh < 2; ++kh) {
        const u16* krow = &K_lds[cur][kh * 32 + lq][0];
        #pragma unroll
        for (int ds = 0; ds < 8; ++ds) {
          s16x8 ak = *(const s16x8*)(krow + ((ds * 16 + hf * 8) ^ swz));
          S[kh] = __builtin_amdgcn_mfma_f32_32x32x16_bf16(ak, aq[ds], S[kh], 0, 0, 0);
        }
      }
      __builtin_amdgcn_s_setprio(0);
      // ---- causal mask: k > q -> -1e30 (C/D map: row=(r&3)+8*(r>>2)+4*hf) ----
      if (kb + 63 > q0w) {
        const int q = q0w + lq;
        #pragma unroll
        for (int kh = 0; kh < 2; ++kh)
          #pragma unroll
          for (int r = 0; r < 16; ++r) {
            int k = kb + kh * 32 + (r & 3) + 8 * (r >> 2) + 4 * hf;
            if (k > q) S[kh][r] = -1e30f;
          }
      }
      // ---- online softmax (in-register trees + cross-half shfl) ----
      f32x16 pm;
      #pragma unroll
      for (int r = 0; r < 16; ++r) pm[r] = fmaxf(S[0][r], S[1][r]);
      float m8[8];
      #pragma unroll
      for (int r = 0; r < 8; ++r) m8[r] = fmaxf(pm[r], pm[r + 8]);
      float mx = fmaxf(fmaxf(fmaxf(m8[0], m8[4]), fmaxf(m8[1], m8[5])),
                       fmaxf(fmaxf(m8[2], m8[6]), fmaxf(m8[3], m8[7])));
      mx = fmaxf(mx, __shfl_xor(mx, 32));
      const float mn = fmaxf(m_r, mx);
      const float al = __expf(m_r - mn);
      m_r = mn;
      #pragma unroll
      for (int kh = 0; kh < 2; ++kh)
        #pragma unroll
        for (int r = 0; r < 16; ++r) S[kh][r] = __expf(S[kh][r] - mn);
      f32x16 sv;
      #pragma unroll
      for (int r = 0; r < 16; ++r) sv[r] = S[0][r] + S[1][r];
      float s8[8];
      #pragma unroll
      for (int r = 0; r < 8; ++r) s8[r] = sv[r] + sv[r + 8];
      float ps = ((s8[0] + s8[4]) + (s8[1] + s8[5])) + ((s8[2] + s8[6]) + (s8[3] + s8[7]));
      ps += __shfl_xor(ps, 32);
      l_r = l_r * al + ps;
      #pragma unroll
      for (int dt = 0; dt < 4; ++dt)
        #pragma unroll
        for (int r = 0; r < 16; ++r) O[dt][r] *= al;
      // ---- P -> LDS (proven swizzled u16x4 path) ----
      // lane holds P[q=lq][k = kh*32 + 8*r2 + 4*hf + (0..3)]; slot = k/8
      u16* pw = &P_lds[w][lq][0];
      #pragma unroll
      for (int kh = 0; kh < 2; ++kh)
        #pragma unroll
        for (int r2 = 0; r2 < 4; ++r2) {
          u16x4 hq;
          #pragma unroll
          for (int j = 0; j < 4; ++j) hq[j] = f2bf(S[kh][r2 * 4 + j]);
          int slot = kh * 4 + r2;
          *(u16x4*)(pw + ((slot ^ pswz) << 3) + hf * 4) = hq;
        }
      asm volatile("s_waitcnt lgkmcnt(0)" ::: "memory");
      __builtin_amdgcn_sched_barrier(0);
      // ---- PV (swapped, 32x32x16): O^T += mfma(V^T, P^T) ----
      s16x8 pb[4];
      #pragma unroll
      for (int ks = 0; ks < 4; ++ks) {
        int slot = ks * 2 + hf;
        pb[ks] = *(const s16x8*)(pw + ((slot ^ pswz) << 3));
      }
      __builtin_amdgcn_s_setprio(1);
      #pragma unroll
      for (int dt = 0; dt < 4; ++dt) {
        const u16* vrow = &V_lds[cur][dt * 32 + lq][0];
        #pragma unroll
        for (int ks = 0; ks < 4; ++ks) {
          s16x8 av = *(const s16x8*)(vrow + ((ks * 16 + hf * 8) ^ swz));
          O[dt] = __builtin_amdgcn_mfma_f32_32x32x16_bf16(av, pb[ks], O[dt], 0, 0, 0);
        }
      }
      __builtin_amdgcn_s_setprio(0);
    }
    asm volatile("s_waitcnt vmcnt(0)" ::: "memory");
    __syncthreads();
  }

  // epilogue: O^T -> attn_out; q = q0w+lq, d = dt*32 + 8*r2 + 4*hf + (0..3)
  const float invl = 1.f / l_r;
  u16* orow = attn_out + (size_t)(b * TSEQ + q0w + lq) * HIDDEN_C + h * HDIM + hf * 4;
  #pragma unroll
  for (int dt = 0; dt < 4; ++dt)
    #pragma unroll
    for (int r2 = 0; r2 < 4; ++r2) {
      u16x4 o4;
      #pragma unroll
      for (int j = 0; j < 4; ++j) o4[j] = f2bf(O[dt][r2 * 4 + j] * invl);
      *(u16x4*)(orow + dt * 32 + r2 * 8) = o4;
    }
}

extern "C" void kernel_launch(void* const* d_in, const int* in_sizes, int n_in,
                              void* d_out, int out_size, void* d_ws, size_t ws_size,
                              hipStream_t stream) {
  const float* x  = (const float*)d_in[0];
  const float* Wq = (const float*)d_in[1];
  const float* Wk = (const float*)d_in[2];
  const float* Wv = (const float*)d_in[3];
  const float* Wo = (const float*)d_in[4];
  float* out = (float*)d_out;
  char* ws = (char*)d_ws;

  u16* xb    = (u16*)(ws);                          // 16 MiB
  u16* wqkvT = (u16*)(ws + (size_t)(16u << 20));    // 12 MiB  [3072][2048]
  u16* woT   = (u16*)(ws + (size_t)(28u << 20));    //  8 MiB  [2048][2048]
  u16* qkv   = (u16*)(ws + (size_t)(36u << 20));    // 24 MiB  [4096][3072]
  u16* vtb   = (u16*)(ws + (size_t)(60u << 20));    //  4 MiB  [2][4][128][2048]
  u16* attn  = (u16*)(ws + (size_t)(64u << 20));    // 16 MiB  [4096][2048]

  dim3 tb(32, 8);
  convert_x_kernel<<<(BTR * HIDDEN_C / 8) / 256, 256, 0, stream>>>(x, xb);
  transpose_w_kernel<<<dim3(HIDDEN_C / 32, HIDDEN_C / 32), tb, 0, stream>>>(Wq, wqkvT, HIDDEN_C, HIDDEN_C);
  transpose_w_kernel<<<dim3(512 / 32, HIDDEN_C / 32), tb, 0, stream>>>(Wk, wqkvT + (size_t)2048 * 2048, HIDDEN_C, 512);
  transpose_w_kernel<<<dim3(512 / 32, HIDDEN_C / 32), tb, 0, stream>>>(Wv, wqkvT + (size_t)2560 * 2048, HIDDEN_C, 512);
  transpose_w_kernel<<<dim3(HIDDEN_C / 32, HIDDEN_C / 32), tb, 0, stream>>>(Wo, woT, HIDDEN_C, HIDDEN_C);

  gemm_bt_kernel<u16><<<dim3(NQKV / 128, BTR / 128), 256, 0, stream>>>(xb, wqkvT, qkv, BTR, NQKV, HIDDEN_C);

  const float scale = 0.53033008588991f;  // 6/sqrt(128)
  rope_kernel<<<(BTR * NHEADS * 4) / 256, 256, 0, stream>>>(qkv, 0, 4, scale);
  rope_kernel<<<(BTR * NKV * 4) / 256, 256, 0, stream>>>(qkv, HIDDEN_C, 2, 1.0f);

  transpose_v_kernel<<<dim3(TSEQ / 32, HDIM / 32, BATCH * NKV), tb, 0, stream>>>(qkv, vtb);

  attn_kernel<<<512, 256, 0, stream>>>(qkv, vtb, attn);

  gemm_bt_kernel<float><<<dim3(HIDDEN_C / 128, BTR / 128), 256, 0, stream>>>(attn, woT, out, BTR, HIDDEN_C, HIDDEN_C);
}

// Round 9
// 234.900 us; speedup vs baseline: 2.2150x; 1.0488x over previous
//
#include <hip/hip_runtime.h>
#include <hip/hip_bf16.h>
#include <cstdint>
#include <cstddef>

typedef unsigned short u16;
typedef short s16x8 __attribute__((ext_vector_type(8)));
typedef float f32x4 __attribute__((ext_vector_type(4)));
typedef float f32x16 __attribute__((ext_vector_type(16)));
typedef u16 u16x4 __attribute__((ext_vector_type(4)));

#define HIDDEN_C 2048
#define TSEQ 2048
#define BATCH 2
#define NHEADS 16
#define NKV 4
#define HDIM 128
#define NQKV 3072
#define BTR 4096  // BATCH*TSEQ
#define QK_SCALE 0.53033008588991f  // 6/sqrt(128)

__device__ __forceinline__ float bf2f(u16 u) {
  union { uint32_t i; float f; } v; v.i = ((uint32_t)u) << 16; return v.f;
}
__device__ __forceinline__ u16 f2bf(float f) {
  union { float f; uint32_t i; } v; v.f = f;
  uint32_t r = v.i + 0x7fffu + ((v.i >> 16) & 1u);
  return (u16)(r >> 16);
}

#define AS1(p) ((__attribute__((address_space(1))) void*)(uintptr_t)(p))
#define AS3(p) ((__attribute__((address_space(3))) void*)(p))

// ---------------- fp32 -> bf16 convert (8 elems/thread) ----------------
__global__ void convert_x_kernel(const float* __restrict__ x, u16* __restrict__ xb) {
  int i = (blockIdx.x * blockDim.x + threadIdx.x) * 8;
  float4 a = *(const float4*)(x + i);
  float4 b = *(const float4*)(x + i + 4);
  uint4 o;
  o.x = (uint32_t)f2bf(a.x) | ((uint32_t)f2bf(a.y) << 16);
  o.y = (uint32_t)f2bf(a.z) | ((uint32_t)f2bf(a.w) << 16);
  o.z = (uint32_t)f2bf(b.x) | ((uint32_t)f2bf(b.y) << 16);
  o.w = (uint32_t)f2bf(b.z) | ((uint32_t)f2bf(b.w) << 16);
  *(uint4*)(xb + i) = o;
}

// ---------------- RoPE cos/sin table: tab[t*16+i] = (cos, sin)(t * f_i) -----
__global__ void rope_table_kernel(float2* __restrict__ tab) {
  int idx = blockIdx.x * blockDim.x + threadIdx.x;
  int t = idx >> 4, i = idx & 15;
  float f = powf(10000.f, -(float)i * (1.f / 16.f));
  float ang = (float)t * f;
  tab[idx] = make_float2(cosf(ang), sinf(ang));
}

// ---------------- W [R][C] fp32 -> W^T [C][R] bf16 ----------------
__global__ void transpose_w_kernel(const float* __restrict__ in, u16* __restrict__ out,
                                   int R, int C) {
  __shared__ float tile[32][33];
  int r0 = blockIdx.y * 32, c0 = blockIdx.x * 32;
  int tx = threadIdx.x, ty = threadIdx.y;
  #pragma unroll
  for (int i = 0; i < 32; i += 8)
    tile[ty + i][tx] = in[(size_t)(r0 + ty + i) * C + c0 + tx];
  __syncthreads();
  #pragma unroll
  for (int i = 0; i < 32; i += 8)
    out[(size_t)(c0 + ty + i) * R + r0 + tx] = f2bf(tile[tx][ty + i]);
}

// ---------------- GEMM: C[M][N] = A[M][K] * BT[N][K]^T (bf16 in, OutT out) ---
// mode=1 (qkv): fused RoPE on head-local cols 0..31 (Q and K regions) + scale
// on Q region, via rope_tab (cols are head-aligned: N tiles of 128 = HDIM).
template <typename OutT>
__global__ __launch_bounds__(256) void gemm_bt_kernel(const u16* __restrict__ A,
                                                      const u16* __restrict__ BT,
                                                      OutT* __restrict__ C,
                                                      int M, int N, int K,
                                                      const float2* __restrict__ tab,
                                                      int mode) {
  __shared__ u16 As[128 * 32];
  __shared__ u16 Bs[128 * 32];
  const int tid = threadIdx.x;
  const int wave = tid >> 6, lane = tid & 63;
  const int lr = lane & 15, lg = lane >> 4;
  const int m0 = blockIdx.y * 128, n0 = blockIdx.x * 128;
  const int wr = wave >> 1, wc = wave & 1;
  f32x4 acc[4][4];
  #pragma unroll
  for (int a = 0; a < 4; ++a)
    #pragma unroll
    for (int b = 0; b < 4; ++b) acc[a][b] = (f32x4){0.f, 0.f, 0.f, 0.f};

  for (int k0 = 0; k0 < K; k0 += 32) {
    #pragma unroll
    for (int i = 0; i < 2; ++i) {
      int c = tid + i * 256;
      int row = c >> 2, col8 = (c & 3) * 8;
      const u16* gA = A + (size_t)(m0 + row) * K + k0 + col8;
      const u16* gB = BT + (size_t)(n0 + row) * K + k0 + col8;
      char* lA = (char*)As + ((size_t)(wave * 64 + i * 256)) * 16;
      char* lB = (char*)Bs + ((size_t)(wave * 64 + i * 256)) * 16;
      __builtin_amdgcn_global_load_lds(AS1(gA), AS3(lA), 16, 0, 0);
      __builtin_amdgcn_global_load_lds(AS1(gB), AS3(lB), 16, 0, 0);
    }
    __syncthreads();
    s16x8 af[4], bfr[4];
    #pragma unroll
    for (int mi = 0; mi < 4; ++mi)
      af[mi] = *(const s16x8*)(As + (wr * 64 + mi * 16 + lr) * 32 + lg * 8);
    #pragma unroll
    for (int ni = 0; ni < 4; ++ni)
      bfr[ni] = *(const s16x8*)(Bs + (wc * 64 + ni * 16 + lr) * 32 + lg * 8);
    #pragma unroll
    for (int mi = 0; mi < 4; ++mi)
      #pragma unroll
      for (int ni = 0; ni < 4; ++ni)
        acc[mi][ni] = __builtin_amdgcn_mfma_f32_16x16x32_bf16(af[mi], bfr[ni], acc[mi][ni], 0, 0, 0);
    __syncthreads();
  }
  // ---- fused RoPE (+ Q scale) for the qkv GEMM ----
  if (mode) {
    if (n0 < 2560 && wc == 0) {
      // head-local cols: ni=0 -> h1[lr] (0..15), ni=1 -> h2[lr] (16..31)
      #pragma unroll
      for (int mi = 0; mi < 4; ++mi) {
        int rowb = m0 + wr * 64 + mi * 16 + lg * 4;
        #pragma unroll
        for (int r = 0; r < 4; ++r) {
          int t = (rowb + r) & (TSEQ - 1);
          float2 cs = tab[(t << 4) | lr];
          float a = acc[mi][0][r], b2 = acc[mi][1][r];
          acc[mi][0][r] = a * cs.x - b2 * cs.y;
          acc[mi][1][r] = b2 * cs.x + a * cs.y;
        }
      }
    }
    if (n0 < 2048) {  // Q region: scale all dims
      #pragma unroll
      for (int mi = 0; mi < 4; ++mi)
        #pragma unroll
        for (int ni = 0; ni < 4; ++ni)
          #pragma unroll
          for (int r = 0; r < 4; ++r) acc[mi][ni][r] *= QK_SCALE;
    }
  }
  #pragma unroll
  for (int mi = 0; mi < 4; ++mi) {
    int rowb = m0 + wr * 64 + mi * 16 + lg * 4;
    #pragma unroll
    for (int ni = 0; ni < 4; ++ni) {
      int col = n0 + wc * 64 + ni * 16 + lr;
      #pragma unroll
      for (int r = 0; r < 4; ++r) {
        float v = acc[mi][ni][r];
        if constexpr (sizeof(OutT) == 2) C[(size_t)(rowb + r) * N + col] = (OutT)f2bf(v);
        else                             C[(size_t)(rowb + r) * N + col] = v;
      }
    }
  }
}

// ---------------- V [b][t][g][d] -> VT [b][g][d][t] ----------------
__global__ void transpose_v_kernel(const u16* __restrict__ qkv, u16* __restrict__ vt) {
  int bg = blockIdx.z;
  int b = bg >> 2, g = bg & 3;
  int t0 = blockIdx.x * 32, d0 = blockIdx.y * 32;
  __shared__ u16 tile[32][33];
  int tx = threadIdx.x, ty = threadIdx.y;
  #pragma unroll
  for (int i = 0; i < 32; i += 8)
    tile[ty + i][tx] = qkv[(size_t)(b * TSEQ + t0 + ty + i) * NQKV + 2560 + g * HDIM + d0 + tx];
  __syncthreads();
  #pragma unroll
  for (int i = 0; i < 32; i += 8)
    vt[((size_t)bg * HDIM + d0 + ty + i) * TSEQ + t0 + tx] = tile[tx][ty + i];
}

// ---------------- flash attention v8: 32x32 swapped MFMA, LDS P path --------
__global__ __launch_bounds__(256, 2) void attn_kernel(const u16* __restrict__ qkv,
                                                      const u16* __restrict__ vt,
                                                      u16* __restrict__ attn_out) {
  __shared__ u16 K_lds[2][64][128];   // [buf][k][d]   32 KB
  __shared__ u16 V_lds[2][128][64];   // [buf][d][k]   32 KB
  __shared__ u16 P_lds[4][32][64];    // [wave][q][k]  16 KB

  const int idx = blockIdx.x;
  const int h = idx & 15, b = (idx >> 4) & 1, g = h >> 2;
  const int jb = (idx >> 5) & 7;
  const int tile = (idx >> 8) ? jb : 15 - jb;   // complementary pairing
  const int tid = threadIdx.x, w = tid >> 6, lane = tid & 63;
  const int lq = lane & 31;        // q (and k/d row) index within 32
  const int hf = lane >> 5;        // lane half
  const int q0 = tile * 128;
  const int q0w = q0 + w * 32;
  const int swz = (lane & 7) << 3; // element-XOR for K/V reads (row = lq)
  const int pswz = lq & 7;         // P slot swizzle key

  const u16* Qg = qkv + (size_t)b * TSEQ * NQKV + h * HDIM;
  const u16* Kg = qkv + (size_t)b * TSEQ * NQKV + HIDDEN_C + g * HDIM;
  const u16* Vg = vt + (size_t)(b * NKV + g) * HDIM * TSEQ;

  // Q frags (B-operand): col q = lq, slot d = ds*16 + hf*8 + j
  s16x8 aq[8];
  {
    const u16* qrow = Qg + (size_t)(q0w + lq) * NQKV + hf * 8;
    #pragma unroll
    for (int ds = 0; ds < 8; ++ds) aq[ds] = *(const s16x8*)(qrow + ds * 16);
  }

  // O^T accumulators: col q = lq, row d = dt*32 + (r&3) + 8*(r>>2) + 4*hf
  f32x16 O[4];
  #pragma unroll
  for (int dt = 0; dt < 4; ++dt)
    #pragma unroll
    for (int r = 0; r < 16; ++r) O[dt][r] = 0.f;
  float m_r = -1e30f, l_r = 0.f;

  auto STAGE = [&](int buf, int kb) {
    #pragma unroll
    for (int i = 0; i < 4; ++i) {          // K: 64 rows x 16 chunks of 16B
      int c = tid + i * 256;
      int row = c >> 4, slot = c & 15;
      int gslot = slot ^ (row & 7);
      const u16* src = Kg + (size_t)(kb + row) * NQKV + gslot * 8;
      char* dst = (char*)&K_lds[buf][0][0] + (size_t)c * 16;
      __builtin_amdgcn_global_load_lds(AS1(src), AS3(dst), 16, 0, 0);
    }
    #pragma unroll
    for (int i = 0; i < 4; ++i) {          // V: 128 rows(d) x 8 chunks of 16B
      int c = tid + i * 256;
      int row = c >> 3, slot = c & 7;
      int gslot = slot ^ (row & 7);
      const u16* src = Vg + (size_t)row * TSEQ + kb + gslot * 8;
      char* dst = (char*)&V_lds[buf][0][0] + (size_t)c * 16;
      __builtin_amdgcn_global_load_lds(AS1(src), AS3(dst), 16, 0, 0);
    }
  };

  const int nt = (q0 + 128) / 64;  // causal: k < q0+128
  STAGE(0, 0);
  asm volatile("s_waitcnt vmcnt(0)" ::: "memory");
  __syncthreads();

  for (int t = 0; t < nt; ++t) {
    const int kb = t * 64;
    const int cur = t & 1;
    if (t + 1 < nt) STAGE(cur ^ 1, kb + 64);

    if (kb <= q0w + 31) {
      // ---- QK^T (swapped, 32x32x16): S^T[k][q] per k-half ----
      f32x16 S[2];
      #pragma unroll
      for (int kh = 0; kh < 2; ++kh)
        #pragma unroll
        for (int r = 0; r < 16; ++r) S[kh][r] = 0.f;
      __builtin_amdgcn_s_setprio(1);
      #pragma unroll
      for (int kh = 0; kh < 2; ++kh) {
        const u16* krow = &K_lds[cur][kh * 32 + lq][0];
        #pragma unroll
        for (int ds = 0; ds < 8; ++ds) {
          s16x8 ak = *(const s16x8*)(krow + ((ds * 16 + hf * 8) ^ swz));
          S[kh] = __builtin_amdgcn_mfma_f32_32x32x16_bf16(ak, aq[ds], S[kh], 0, 0, 0);
        }
      }
      __builtin_amdgcn_s_setprio(0);
      // ---- causal mask: k > q -> -1e30 (C/D map: row=(r&3)+8*(r>>2)+4*hf) ----
      if (kb + 63 > q0w) {
        const int q = q0w + lq;
        #pragma unroll
        for (int kh = 0; kh < 2; ++kh)
          #pragma unroll
          for (int r = 0; r < 16; ++r) {
            int k = kb + kh * 32 + (r & 3) + 8 * (r >> 2) + 4 * hf;
            if (k > q) S[kh][r] = -1e30f;
          }
      }
      // ---- online softmax (in-register trees + cross-half shfl) ----
      f32x16 pm;
      #pragma unroll
      for (int r = 0; r < 16; ++r) pm[r] = fmaxf(S[0][r], S[1][r]);
      float m8[8];
      #pragma unroll
      for (int r = 0; r < 8; ++r) m8[r] = fmaxf(pm[r], pm[r + 8]);
      float mx = fmaxf(fmaxf(fmaxf(m8[0], m8[4]), fmaxf(m8[1], m8[5])),
                       fmaxf(fmaxf(m8[2], m8[6]), fmaxf(m8[3], m8[7])));
      mx = fmaxf(mx, __shfl_xor(mx, 32));
      const float mn = fmaxf(m_r, mx);
      const float al = __expf(m_r - mn);
      m_r = mn;
      #pragma unroll
      for (int kh = 0; kh < 2; ++kh)
        #pragma unroll
        for (int r = 0; r < 16; ++r) S[kh][r] = __expf(S[kh][r] - mn);
      f32x16 sv;
      #pragma unroll
      for (int r = 0; r < 16; ++r) sv[r] = S[0][r] + S[1][r];
      float s8[8];
      #pragma unroll
      for (int r = 0; r < 8; ++r) s8[r] = sv[r] + sv[r + 8];
      float ps = ((s8[0] + s8[4]) + (s8[1] + s8[5])) + ((s8[2] + s8[6]) + (s8[3] + s8[7]));
      ps += __shfl_xor(ps, 32);
      l_r = l_r * al + ps;
      #pragma unroll
      for (int dt = 0; dt < 4; ++dt)
        #pragma unroll
        for (int r = 0; r < 16; ++r) O[dt][r] *= al;
      // ---- P -> LDS (proven swizzled u16x4 path) ----
      u16* pw = &P_lds[w][lq][0];
      #pragma unroll
      for (int kh = 0; kh < 2; ++kh)
        #pragma unroll
        for (int r2 = 0; r2 < 4; ++r2) {
          u16x4 hq;
          #pragma unroll
          for (int j = 0; j < 4; ++j) hq[j] = f2bf(S[kh][r2 * 4 + j]);
          int slot = kh * 4 + r2;
          *(u16x4*)(pw + ((slot ^ pswz) << 3) + hf * 4) = hq;
        }
      asm volatile("s_waitcnt lgkmcnt(0)" ::: "memory");
      __builtin_amdgcn_sched_barrier(0);
      // ---- PV (swapped, 32x32x16): O^T += mfma(V^T, P^T) ----
      s16x8 pb[4];
      #pragma unroll
      for (int ks = 0; ks < 4; ++ks) {
        int slot = ks * 2 + hf;
        pb[ks] = *(const s16x8*)(pw + ((slot ^ pswz) << 3));
      }
      __builtin_amdgcn_s_setprio(1);
      #pragma unroll
      for (int dt = 0; dt < 4; ++dt) {
        const u16* vrow = &V_lds[cur][dt * 32 + lq][0];
        #pragma unroll
        for (int ks = 0; ks < 4; ++ks) {
          s16x8 av = *(const s16x8*)(vrow + ((ks * 16 + hf * 8) ^ swz));
          O[dt] = __builtin_amdgcn_mfma_f32_32x32x16_bf16(av, pb[ks], O[dt], 0, 0, 0);
        }
      }
      __builtin_amdgcn_s_setprio(0);
    }
    asm volatile("s_waitcnt vmcnt(0)" ::: "memory");
    __syncthreads();
  }

  // epilogue: O^T -> attn_out; q = q0w+lq, d = dt*32 + 8*r2 + 4*hf + (0..3)
  const float invl = 1.f / l_r;
  u16* orow = attn_out + (size_t)(b * TSEQ + q0w + lq) * HIDDEN_C + h * HDIM + hf * 4;
  #pragma unroll
  for (int dt = 0; dt < 4; ++dt)
    #pragma unroll
    for (int r2 = 0; r2 < 4; ++r2) {
      u16x4 o4;
      #pragma unroll
      for (int j = 0; j < 4; ++j) o4[j] = f2bf(O[dt][r2 * 4 + j] * invl);
      *(u16x4*)(orow + dt * 32 + r2 * 8) = o4;
    }
}

extern "C" void kernel_launch(void* const* d_in, const int* in_sizes, int n_in,
                              void* d_out, int out_size, void* d_ws, size_t ws_size,
                              hipStream_t stream) {
  const float* x  = (const float*)d_in[0];
  const float* Wq = (const float*)d_in[1];
  const float* Wk = (const float*)d_in[2];
  const float* Wv = (const float*)d_in[3];
  const float* Wo = (const float*)d_in[4];
  float* out = (float*)d_out;
  char* ws = (char*)d_ws;

  u16* xb    = (u16*)(ws);                          // 16 MiB
  u16* wqkvT = (u16*)(ws + (size_t)(16u << 20));    // 12 MiB  [3072][2048]
  u16* woT   = (u16*)(ws + (size_t)(28u << 20));    //  8 MiB  [2048][2048]
  u16* qkv   = (u16*)(ws + (size_t)(36u << 20));    // 24 MiB  [4096][3072]
  u16* vtb   = (u16*)(ws + (size_t)(60u << 20));    //  4 MiB  [2][4][128][2048]
  u16* attn  = (u16*)(ws + (size_t)(64u << 20));    // 16 MiB  [4096][2048]
  // rope table overlaps the attn buffer: consumed by the QKV GEMM (before
  // attn_kernel writes the region), rebuilt every launch -> deterministic.
  float2* rope_tab = (float2*)(ws + (size_t)(64u << 20));  // 256 KiB

  dim3 tb(32, 8);
  convert_x_kernel<<<(BTR * HIDDEN_C / 8) / 256, 256, 0, stream>>>(x, xb);
  rope_table_kernel<<<(TSEQ * 16) / 256, 256, 0, stream>>>(rope_tab);
  transpose_w_kernel<<<dim3(HIDDEN_C / 32, HIDDEN_C / 32), tb, 0, stream>>>(Wq, wqkvT, HIDDEN_C, HIDDEN_C);
  transpose_w_kernel<<<dim3(512 / 32, HIDDEN_C / 32), tb, 0, stream>>>(Wk, wqkvT + (size_t)2048 * 2048, HIDDEN_C, 512);
  transpose_w_kernel<<<dim3(512 / 32, HIDDEN_C / 32), tb, 0, stream>>>(Wv, wqkvT + (size_t)2560 * 2048, HIDDEN_C, 512);
  transpose_w_kernel<<<dim3(HIDDEN_C / 32, HIDDEN_C / 32), tb, 0, stream>>>(Wo, woT, HIDDEN_C, HIDDEN_C);

  gemm_bt_kernel<u16><<<dim3(NQKV / 128, BTR / 128), 256, 0, stream>>>(
      xb, wqkvT, qkv, BTR, NQKV, HIDDEN_C, rope_tab, 1);

  transpose_v_kernel<<<dim3(TSEQ / 32, HDIM / 32, BATCH * NKV), tb, 0, stream>>>(qkv, vtb);

  attn_kernel<<<512, 256, 0, stream>>>(qkv, vtb, attn);

  gemm_bt_kernel<float><<<dim3(HIDDEN_C / 128, BTR / 128), 256, 0, stream>>>(
      attn, woT, out, BTR, HIDDEN_C, HIDDEN_C, nullptr, 0);
}

// Round 10
// 210.834 us; speedup vs baseline: 2.4679x; 1.1141x over previous
//
#include <hip/hip_runtime.h>
#include <hip/hip_bf16.h>
#include <cstdint>
#include <cstddef>

typedef unsigned short u16;
typedef short s16x8 __attribute__((ext_vector_type(8)));
typedef float f32x4 __attribute__((ext_vector_type(4)));
typedef float f32x16 __attribute__((ext_vector_type(16)));
typedef u16 u16x4 __attribute__((ext_vector_type(4)));

#define HIDDEN_C 2048
#define TSEQ 2048
#define BATCH 2
#define NHEADS 16
#define NKV 4
#define HDIM 128
#define NQKV 3072
#define BTR 4096  // BATCH*TSEQ
#define QK_SCALE 0.53033008588991f  // 6/sqrt(128)

__device__ __forceinline__ float bf2f(u16 u) {
  union { uint32_t i; float f; } v; v.i = ((uint32_t)u) << 16; return v.f;
}
__device__ __forceinline__ u16 f2bf(float f) {
  union { float f; uint32_t i; } v; v.f = f;
  uint32_t r = v.i + 0x7fffu + ((v.i >> 16) & 1u);
  return (u16)(r >> 16);
}

#define AS1(p) ((__attribute__((address_space(1))) void*)(uintptr_t)(p))
#define AS3(p) ((__attribute__((address_space(3))) void*)(p))

// ------- fp32 -> bf16 convert (8 elems/thread) + RoPE table (first blocks) ---
__global__ void convert_x_kernel(const float* __restrict__ x, u16* __restrict__ xb,
                                 float2* __restrict__ tab) {
  int gi = blockIdx.x * blockDim.x + threadIdx.x;
  if (gi < TSEQ * 16) {  // rope table: tab[t*16+i] = (cos,sin)(t * f_i)
    int t = gi >> 4, i = gi & 15;
    float f = powf(10000.f, -(float)i * (1.f / 16.f));
    float ang = (float)t * f;
    tab[gi] = make_float2(cosf(ang), sinf(ang));
  }
  int i = gi * 8;
  float4 a = *(const float4*)(x + i);
  float4 b = *(const float4*)(x + i + 4);
  uint4 o;
  o.x = (uint32_t)f2bf(a.x) | ((uint32_t)f2bf(a.y) << 16);
  o.y = (uint32_t)f2bf(a.z) | ((uint32_t)f2bf(a.w) << 16);
  o.z = (uint32_t)f2bf(b.x) | ((uint32_t)f2bf(b.y) << 16);
  o.w = (uint32_t)f2bf(b.z) | ((uint32_t)f2bf(b.w) << 16);
  *(uint4*)(xb + i) = o;
}

// ------- fused W transposes: z selects {Wq,Wk,Wv,Wo}; out row len = 2048 -----
__global__ void transpose_w_kernel(const float* __restrict__ Wq,
                                   const float* __restrict__ Wk,
                                   const float* __restrict__ Wv,
                                   const float* __restrict__ Wo,
                                   u16* __restrict__ wqkvT,
                                   u16* __restrict__ woT) {
  const int z = blockIdx.z;
  const float* in; u16* out; int C;
  switch (z) {
    case 0: in = Wq; out = wqkvT;                        C = 2048; break;
    case 1: in = Wk; out = wqkvT + (size_t)2048 * 2048;  C = 512;  break;
    case 2: in = Wv; out = wqkvT + (size_t)2560 * 2048;  C = 512;  break;
    default: in = Wo; out = woT;                         C = 2048; break;
  }
  int r0 = blockIdx.y * 32, c0 = blockIdx.x * 32;
  if (c0 >= C) return;
  __shared__ float tile[32][33];
  int tx = threadIdx.x, ty = threadIdx.y;
  #pragma unroll
  for (int i = 0; i < 32; i += 8)
    tile[ty + i][tx] = in[(size_t)(r0 + ty + i) * C + c0 + tx];
  __syncthreads();
  #pragma unroll
  for (int i = 0; i < 32; i += 8)
    out[(size_t)(c0 + ty + i) * 2048 + r0 + tx] = f2bf(tile[tx][ty + i]);
}

// ---------------- GEMM: C[M][N] = A[M][K] * BT[N][K]^T (bf16 in, OutT out) ---
// BK=64, LDS XOR-swizzled (slot^(row&7), 16B slots); frags read per-kk.
// mode=1 (qkv): fused RoPE on head-local cols 0..31 + scale on Q region.
template <typename OutT>
__global__ __launch_bounds__(256) void gemm_bt_kernel(const u16* __restrict__ A,
                                                      const u16* __restrict__ BT,
                                                      OutT* __restrict__ C,
                                                      int M, int N, int K,
                                                      const float2* __restrict__ tab,
                                                      int mode) {
  __shared__ u16 As[128 * 64];
  __shared__ u16 Bs[128 * 64];
  const int tid = threadIdx.x;
  const int wave = tid >> 6, lane = tid & 63;
  const int lr = lane & 15, lg = lane >> 4;
  const int m0 = blockIdx.y * 128, n0 = blockIdx.x * 128;
  const int wr = wave >> 1, wc = wave & 1;
  const int fsw = (lr & 7) << 3;  // frag-read element XOR
  f32x4 acc[4][4];
  #pragma unroll
  for (int a = 0; a < 4; ++a)
    #pragma unroll
    for (int b = 0; b < 4; ++b) acc[a][b] = (f32x4){0.f, 0.f, 0.f, 0.f};

  for (int k0 = 0; k0 < K; k0 += 64) {
    #pragma unroll
    for (int i = 0; i < 4; ++i) {
      int c = tid + i * 256;              // 1024 chunks of 16B per matrix
      int row = c >> 3, slot = c & 7;     // 8 slots per 64-elem row
      int gslot = slot ^ (row & 7);
      const u16* gA = A + (size_t)(m0 + row) * K + k0 + gslot * 8;
      const u16* gB = BT + (size_t)(n0 + row) * K + k0 + gslot * 8;
      char* lA = (char*)As + (size_t)c * 16;
      char* lB = (char*)Bs + (size_t)c * 16;
      __builtin_amdgcn_global_load_lds(AS1(gA), AS3(lA), 16, 0, 0);
      __builtin_amdgcn_global_load_lds(AS1(gB), AS3(lB), 16, 0, 0);
    }
    __syncthreads();
    #pragma unroll
    for (int kk = 0; kk < 2; ++kk) {
      s16x8 af[4], bfr[4];
      #pragma unroll
      for (int mi = 0; mi < 4; ++mi)
        af[mi] = *(const s16x8*)(As + (wr * 64 + mi * 16 + lr) * 64 + ((kk * 32 + lg * 8) ^ fsw));
      #pragma unroll
      for (int ni = 0; ni < 4; ++ni)
        bfr[ni] = *(const s16x8*)(Bs + (wc * 64 + ni * 16 + lr) * 64 + ((kk * 32 + lg * 8) ^ fsw));
      #pragma unroll
      for (int mi = 0; mi < 4; ++mi)
        #pragma unroll
        for (int ni = 0; ni < 4; ++ni)
          acc[mi][ni] = __builtin_amdgcn_mfma_f32_16x16x32_bf16(af[mi], bfr[ni], acc[mi][ni], 0, 0, 0);
    }
    __syncthreads();
  }
  // ---- fused RoPE (+ Q scale) for the qkv GEMM ----
  if (mode) {
    if (n0 < 2560 && wc == 0) {
      #pragma unroll
      for (int mi = 0; mi < 4; ++mi) {
        int rowb = m0 + wr * 64 + mi * 16 + lg * 4;
        #pragma unroll
        for (int r = 0; r < 4; ++r) {
          int t = (rowb + r) & (TSEQ - 1);
          float2 cs = tab[(t << 4) | lr];
          float a = acc[mi][0][r], b2 = acc[mi][1][r];
          acc[mi][0][r] = a * cs.x - b2 * cs.y;
          acc[mi][1][r] = b2 * cs.x + a * cs.y;
        }
      }
    }
    if (n0 < 2048) {
      #pragma unroll
      for (int mi = 0; mi < 4; ++mi)
        #pragma unroll
        for (int ni = 0; ni < 4; ++ni)
          #pragma unroll
          for (int r = 0; r < 4; ++r) acc[mi][ni][r] *= QK_SCALE;
    }
  }
  #pragma unroll
  for (int mi = 0; mi < 4; ++mi) {
    int rowb = m0 + wr * 64 + mi * 16 + lg * 4;
    #pragma unroll
    for (int ni = 0; ni < 4; ++ni) {
      int col = n0 + wc * 64 + ni * 16 + lr;
      #pragma unroll
      for (int r = 0; r < 4; ++r) {
        float v = acc[mi][ni][r];
        if constexpr (sizeof(OutT) == 2) C[(size_t)(rowb + r) * N + col] = (OutT)f2bf(v);
        else                             C[(size_t)(rowb + r) * N + col] = v;
      }
    }
  }
}

// ---------------- V [b][t][g][d] -> VT [b][g][d][t] ----------------
__global__ void transpose_v_kernel(const u16* __restrict__ qkv, u16* __restrict__ vt) {
  int bg = blockIdx.z;
  int b = bg >> 2, g = bg & 3;
  int t0 = blockIdx.x * 32, d0 = blockIdx.y * 32;
  __shared__ u16 tile[32][33];
  int tx = threadIdx.x, ty = threadIdx.y;
  #pragma unroll
  for (int i = 0; i < 32; i += 8)
    tile[ty + i][tx] = qkv[(size_t)(b * TSEQ + t0 + ty + i) * NQKV + 2560 + g * HDIM + d0 + tx];
  __syncthreads();
  #pragma unroll
  for (int i = 0; i < 32; i += 8)
    vt[((size_t)bg * HDIM + d0 + ty + i) * TSEQ + t0 + tx] = tile[tx][ty + i];
}

// ---------------- flash attention v8: 32x32 swapped MFMA, LDS P path --------
__global__ __launch_bounds__(256, 2) void attn_kernel(const u16* __restrict__ qkv,
                                                      const u16* __restrict__ vt,
                                                      u16* __restrict__ attn_out) {
  __shared__ u16 K_lds[2][64][128];   // [buf][k][d]   32 KB
  __shared__ u16 V_lds[2][128][64];   // [buf][d][k]   32 KB
  __shared__ u16 P_lds[4][32][64];    // [wave][q][k]  16 KB

  const int idx = blockIdx.x;
  const int h = idx & 15, b = (idx >> 4) & 1, g = h >> 2;
  const int jb = (idx >> 5) & 7;
  const int tile = (idx >> 8) ? jb : 15 - jb;   // complementary pairing
  const int tid = threadIdx.x, w = tid >> 6, lane = tid & 63;
  const int lq = lane & 31;        // q (and k/d row) index within 32
  const int hf = lane >> 5;        // lane half
  const int q0 = tile * 128;
  const int q0w = q0 + w * 32;
  const int swz = (lane & 7) << 3; // element-XOR for K/V reads (row = lq)
  const int pswz = lq & 7;         // P slot swizzle key

  const u16* Qg = qkv + (size_t)b * TSEQ * NQKV + h * HDIM;
  const u16* Kg = qkv + (size_t)b * TSEQ * NQKV + HIDDEN_C + g * HDIM;
  const u16* Vg = vt + (size_t)(b * NKV + g) * HDIM * TSEQ;

  // Q frags (B-operand): col q = lq, slot d = ds*16 + hf*8 + j
  s16x8 aq[8];
  {
    const u16* qrow = Qg + (size_t)(q0w + lq) * NQKV + hf * 8;
    #pragma unroll
    for (int ds = 0; ds < 8; ++ds) aq[ds] = *(const s16x8*)(qrow + ds * 16);
  }

  // O^T accumulators: col q = lq, row d = dt*32 + (r&3) + 8*(r>>2) + 4*hf
  f32x16 O[4];
  #pragma unroll
  for (int dt = 0; dt < 4; ++dt)
    #pragma unroll
    for (int r = 0; r < 16; ++r) O[dt][r] = 0.f;
  float m_r = -1e30f, l_r = 0.f;

  auto STAGE = [&](int buf, int kb) {
    #pragma unroll
    for (int i = 0; i < 4; ++i) {          // K: 64 rows x 16 chunks of 16B
      int c = tid + i * 256;
      int row = c >> 4, slot = c & 15;
      int gslot = slot ^ (row & 7);
      const u16* src = Kg + (size_t)(kb + row) * NQKV + gslot * 8;
      char* dst = (char*)&K_lds[buf][0][0] + (size_t)c * 16;
      __builtin_amdgcn_global_load_lds(AS1(src), AS3(dst), 16, 0, 0);
    }
    #pragma unroll
    for (int i = 0; i < 4; ++i) {          // V: 128 rows(d) x 8 chunks of 16B
      int c = tid + i * 256;
      int row = c >> 3, slot = c & 7;
      int gslot = slot ^ (row & 7);
      const u16* src = Vg + (size_t)row * TSEQ + kb + gslot * 8;
      char* dst = (char*)&V_lds[buf][0][0] + (size_t)c * 16;
      __builtin_amdgcn_global_load_lds(AS1(src), AS3(dst), 16, 0, 0);
    }
  };

  const int nt = (q0 + 128) / 64;  // causal: k < q0+128
  STAGE(0, 0);
  asm volatile("s_waitcnt vmcnt(0)" ::: "memory");
  __syncthreads();

  for (int t = 0; t < nt; ++t) {
    const int kb = t * 64;
    const int cur = t & 1;
    if (t + 1 < nt) STAGE(cur ^ 1, kb + 64);

    if (kb <= q0w + 31) {
      // ---- QK^T (swapped, 32x32x16): S^T[k][q] per k-half ----
      f32x16 S[2];
      #pragma unroll
      for (int kh = 0; kh < 2; ++kh)
        #pragma unroll
        for (int r = 0; r < 16; ++r) S[kh][r] = 0.f;
      __builtin_amdgcn_s_setprio(1);
      #pragma unroll
      for (int kh = 0; kh < 2; ++kh) {
        const u16* krow = &K_lds[cur][kh * 32 + lq][0];
        #pragma unroll
        for (int ds = 0; ds < 8; ++ds) {
          s16x8 ak = *(const s16x8*)(krow + ((ds * 16 + hf * 8) ^ swz));
          S[kh] = __builtin_amdgcn_mfma_f32_32x32x16_bf16(ak, aq[ds], S[kh], 0, 0, 0);
        }
      }
      __builtin_amdgcn_s_setprio(0);
      // ---- causal mask: k > q -> -1e30 (C/D map: row=(r&3)+8*(r>>2)+4*hf) ----
      if (kb + 63 > q0w) {
        const int q = q0w + lq;
        #pragma unroll
        for (int kh = 0; kh < 2; ++kh)
          #pragma unroll
          for (int r = 0; r < 16; ++r) {
            int k = kb + kh * 32 + (r & 3) + 8 * (r >> 2) + 4 * hf;
            if (k > q) S[kh][r] = -1e30f;
          }
      }
      // ---- online softmax (in-register trees + cross-half shfl) ----
      f32x16 pm;
      #pragma unroll
      for (int r = 0; r < 16; ++r) pm[r] = fmaxf(S[0][r], S[1][r]);
      float m8[8];
      #pragma unroll
      for (int r = 0; r < 8; ++r) m8[r] = fmaxf(pm[r], pm[r + 8]);
      float mx = fmaxf(fmaxf(fmaxf(m8[0], m8[4]), fmaxf(m8[1], m8[5])),
                       fmaxf(fmaxf(m8[2], m8[6]), fmaxf(m8[3], m8[7])));
      mx = fmaxf(mx, __shfl_xor(mx, 32));
      const float mn = fmaxf(m_r, mx);
      const float al = __expf(m_r - mn);
      m_r = mn;
      #pragma unroll
      for (int kh = 0; kh < 2; ++kh)
        #pragma unroll
        for (int r = 0; r < 16; ++r) S[kh][r] = __expf(S[kh][r] - mn);
      f32x16 sv;
      #pragma unroll
      for (int r = 0; r < 16; ++r) sv[r] = S[0][r] + S[1][r];
      float s8[8];
      #pragma unroll
      for (int r = 0; r < 8; ++r) s8[r] = sv[r] + sv[r + 8];
      float ps = ((s8[0] + s8[4]) + (s8[1] + s8[5])) + ((s8[2] + s8[6]) + (s8[3] + s8[7]));
      ps += __shfl_xor(ps, 32);
      l_r = l_r * al + ps;
      #pragma unroll
      for (int dt = 0; dt < 4; ++dt)
        #pragma unroll
        for (int r = 0; r < 16; ++r) O[dt][r] *= al;
      // ---- P -> LDS (proven swizzled u16x4 path) ----
      u16* pw = &P_lds[w][lq][0];
      #pragma unroll
      for (int kh = 0; kh < 2; ++kh)
        #pragma unroll
        for (int r2 = 0; r2 < 4; ++r2) {
          u16x4 hq;
          #pragma unroll
          for (int j = 0; j < 4; ++j) hq[j] = f2bf(S[kh][r2 * 4 + j]);
          int slot = kh * 4 + r2;
          *(u16x4*)(pw + ((slot ^ pswz) << 3) + hf * 4) = hq;
        }
      asm volatile("s_waitcnt lgkmcnt(0)" ::: "memory");
      __builtin_amdgcn_sched_barrier(0);
      // ---- PV (swapped, 32x32x16): O^T += mfma(V^T, P^T) ----
      s16x8 pb[4];
      #pragma unroll
      for (int ks = 0; ks < 4; ++ks) {
        int slot = ks * 2 + hf;
        pb[ks] = *(const s16x8*)(pw + ((slot ^ pswz) << 3));
      }
      __builtin_amdgcn_s_setprio(1);
      #pragma unroll
      for (int dt = 0; dt < 4; ++dt) {
        const u16* vrow = &V_lds[cur][dt * 32 + lq][0];
        #pragma unroll
        for (int ks = 0; ks < 4; ++ks) {
          s16x8 av = *(const s16x8*)(vrow + ((ks * 16 + hf * 8) ^ swz));
          O[dt] = __builtin_amdgcn_mfma_f32_32x32x16_bf16(av, pb[ks], O[dt], 0, 0, 0);
        }
      }
      __builtin_amdgcn_s_setprio(0);
    }
    asm volatile("s_waitcnt vmcnt(0)" ::: "memory");
    __syncthreads();
  }

  // epilogue: O^T -> attn_out; q = q0w+lq, d = dt*32 + 8*r2 + 4*hf + (0..3)
  const float invl = 1.f / l_r;
  u16* orow = attn_out + (size_t)(b * TSEQ + q0w + lq) * HIDDEN_C + h * HDIM + hf * 4;
  #pragma unroll
  for (int dt = 0; dt < 4; ++dt)
    #pragma unroll
    for (int r2 = 0; r2 < 4; ++r2) {
      u16x4 o4;
      #pragma unroll
      for (int j = 0; j < 4; ++j) o4[j] = f2bf(O[dt][r2 * 4 + j] * invl);
      *(u16x4*)(orow + dt * 32 + r2 * 8) = o4;
    }
}

extern "C" void kernel_launch(void* const* d_in, const int* in_sizes, int n_in,
                              void* d_out, int out_size, void* d_ws, size_t ws_size,
                              hipStream_t stream) {
  const float* x  = (const float*)d_in[0];
  const float* Wq = (const float*)d_in[1];
  const float* Wk = (const float*)d_in[2];
  const float* Wv = (const float*)d_in[3];
  const float* Wo = (const float*)d_in[4];
  float* out = (float*)d_out;
  char* ws = (char*)d_ws;

  u16* xb    = (u16*)(ws);                          // 16 MiB
  u16* wqkvT = (u16*)(ws + (size_t)(16u << 20));    // 12 MiB  [3072][2048]
  u16* woT   = (u16*)(ws + (size_t)(28u << 20));    //  8 MiB  [2048][2048]
  u16* qkv   = (u16*)(ws + (size_t)(36u << 20));    // 24 MiB  [4096][3072]
  u16* vtb   = (u16*)(ws + (size_t)(60u << 20));    //  4 MiB  [2][4][128][2048]
  u16* attn  = (u16*)(ws + (size_t)(64u << 20));    // 16 MiB  [4096][2048]
  // rope table overlaps the attn buffer: consumed by the QKV GEMM (before
  // attn_kernel writes the region), rebuilt every launch -> deterministic.
  float2* rope_tab = (float2*)(ws + (size_t)(64u << 20));  // 256 KiB

  dim3 tb(32, 8);
  convert_x_kernel<<<(BTR * HIDDEN_C / 8) / 256, 256, 0, stream>>>(x, xb, rope_tab);
  transpose_w_kernel<<<dim3(64, 64, 4), tb, 0, stream>>>(Wq, Wk, Wv, Wo, wqkvT, woT);

  gemm_bt_kernel<u16><<<dim3(NQKV / 128, BTR / 128), 256, 0, stream>>>(
      xb, wqkvT, qkv, BTR, NQKV, HIDDEN_C, rope_tab, 1);

  transpose_v_kernel<<<dim3(TSEQ / 32, HDIM / 32, BATCH * NKV), tb, 0, stream>>>(qkv, vtb);

  attn_kernel<<<512, 256, 0, stream>>>(qkv, vtb, attn);

  gemm_bt_kernel<float><<<dim3(HIDDEN_C / 128, BTR / 128), 256, 0, stream>>>(
      attn, woT, out, BTR, HIDDEN_C, HIDDEN_C, nullptr, 0);
}